// Round 16
// baseline (213.217 us; speedup 1.0000x reference)
//
#include <hip/hip_runtime.h>
#include <hip/hip_bf16.h>
#include <hip/hip_fp8.h>
#include <math.h>

typedef __attribute__((ext_vector_type(4))) float f32x4;

#define NB 4096
#define ND 1024
#define INV_T 14.2857142857142857f   // 1/0.07

__device__ inline float fp82f(unsigned char b) {
    __hip_fp8_e4m3 h; h.__x = b;
    return (float)h;
}
__device__ inline void gload16(const void* g, void* l) {
    __builtin_amdgcn_global_load_lds(
        (const __attribute__((address_space(1))) void*)g,
        (__attribute__((address_space(3))) void*)l, 16, 0, 0);
}

// ---------------- kernel 0: L2-normalize rows, cast to fp8 e4m3 -------------
__global__ __launch_bounds__(256) void norm_kernel(
        const float* __restrict__ M, const float* __restrict__ P,
        unsigned char* __restrict__ Mf, unsigned char* __restrict__ Pf) {
    int row = blockIdx.x & (NB - 1);
    const float* src = (blockIdx.x < NB) ? M : P;
    unsigned char* dst = (blockIdx.x < NB) ? Mf : Pf;
    int tid = threadIdx.x;
    float4 v = ((const float4*)(src + (size_t)row * ND))[tid];
    float ss = v.x * v.x + v.y * v.y + v.z * v.z + v.w * v.w;
    for (int off = 32; off; off >>= 1) ss += __shfl_down(ss, off);
    __shared__ float red[4];
    int lane = tid & 63, w = tid >> 6;
    if (lane == 0) red[w] = ss;
    __syncthreads();
    float rn = rsqrtf(red[0] + red[1] + red[2] + red[3]);
    int p = __builtin_amdgcn_cvt_pk_fp8_f32(v.x * rn, v.y * rn, 0, false);
    p = __builtin_amdgcn_cvt_pk_fp8_f32(v.z * rn, v.w * rn, p, true);
    ((int*)dst)[row * 256 + tid] = p;
}

// ---------------- kernel 1: per-row mask codes ------------------------------
__global__ __launch_bounds__(256) void key_kernel(
        const int* __restrict__ labels, const int* __restrict__ sm,
        const int* __restrict__ sp, int* __restrict__ code) {
    int i = blockIdx.x * 256 + threadIdx.x;
    if (i < NB) {
        int l = labels[i];
        code[i] = (l == 0) ? 0x40000000 : (1 + l + (sm[i] << 8) + (sp[i] << 16));
    }
}

// ------- kernel 2: fused row-sum + normalized masked weight matrix (fp8) ----
__global__ __launch_bounds__(256) void rowsumw_kernel(
        const float* __restrict__ cs, const int* __restrict__ code,
        unsigned char* __restrict__ W, float* __restrict__ flag) {
    int i = blockIdx.x;
    int ci = code[i];
    int tid = threadIdx.x;
    const float4* row = (const float4*)(cs + (size_t)i * NB);
    const int4* c4 = (const int4*)code;
    float4 v[4];
    int4 cj[4];
    float s = 0.f;
#pragma unroll
    for (int k = 0; k < 4; ++k) {
        int t = tid + k * 256;
        v[k] = row[t];
        cj[k] = c4[t];
        int j = t * 4;
        if (cj[k].x == ci && j + 0 != i) s += v[k].x;
        if (cj[k].y == ci && j + 1 != i) s += v[k].y;
        if (cj[k].z == ci && j + 2 != i) s += v[k].z;
        if (cj[k].w == ci && j + 3 != i) s += v[k].w;
    }
    for (int off = 1; off < 64; off <<= 1) s += __shfl_xor(s, off);
    __shared__ float red[4];
    int lane = tid & 63, w = tid >> 6;
    if (lane == 0) red[w] = s;
    __syncthreads();
    float tot = red[0] + red[1] + red[2] + red[3];
    float inv = (tot > 0.f) ? 1.f / tot : 0.f;
#pragma unroll
    for (int k = 0; k < 4; ++k) {
        int t = tid + k * 256;
        int j = t * 4;
        float f0 = (cj[k].x == ci && j + 0 != i) ? v[k].x * inv : 0.f;
        float f1 = (cj[k].y == ci && j + 1 != i) ? v[k].y * inv : 0.f;
        float f2 = (cj[k].z == ci && j + 2 != i) ? v[k].z * inv : 0.f;
        float f3 = (cj[k].w == ci && j + 3 != i) ? v[k].w * inv : 0.f;
        int p = __builtin_amdgcn_cvt_pk_fp8_f32(f0, f1, 0, false);
        p = __builtin_amdgcn_cvt_pk_fp8_f32(f2, f3, p, true);
        ((int*)W)[((size_t)i * NB + j) >> 2] = p;
    }
    if (tid == 0) flag[i] = (tot > 0.f) ? 1.f : 0.f;
}

// ------- kernel 2b: in-place symmetrize W -> Wsym = W + W^T (fp8) -----------
// 2080 blocks, one per unordered 64x64-tile pair (ti<=tj).
__global__ __launch_bounds__(256) void symw_kernel(unsigned char* __restrict__ W) {
    __shared__ unsigned char Ta[64][80], Tb[64][80];   // 80 = 5*16, aligned
    int b = blockIdx.x;
    int ti = 0, t = b;
    while (t >= 64 - ti) { t -= 64 - ti; ++ti; }
    int tj = ti + t;
    size_t ra = (size_t)ti * 64, rb = (size_t)tj * 64;
    int tid = threadIdx.x;
    int r = tid >> 2, c0 = (tid & 3) * 16;
    int4 a0 = *(const int4*)&W[(ra + r) * NB + rb + c0];
    int4 b0 = *(const int4*)&W[(rb + r) * NB + ra + c0];
    *(int4*)&Ta[r][c0] = a0;
    *(int4*)&Tb[r][c0] = b0;
    __syncthreads();
    unsigned char oa[16], ob[16];
#pragma unroll
    for (int c = 0; c < 16; c += 2) {
        int cc = c0 + c;
        float a_lo = fp82f(Ta[r][cc])     + fp82f(Tb[cc][r]);
        float a_hi = fp82f(Ta[r][cc + 1]) + fp82f(Tb[cc + 1][r]);
        float b_lo = fp82f(Tb[r][cc])     + fp82f(Ta[cc][r]);
        float b_hi = fp82f(Tb[r][cc + 1]) + fp82f(Ta[cc + 1][r]);
        int pa = __builtin_amdgcn_cvt_pk_fp8_f32(a_lo, a_hi, 0, false);
        int pb = __builtin_amdgcn_cvt_pk_fp8_f32(b_lo, b_hi, 0, false);
        oa[c] = (unsigned char)(pa & 0xff); oa[c + 1] = (unsigned char)((pa >> 8) & 0xff);
        ob[c] = (unsigned char)(pb & 0xff); ob[c + 1] = (unsigned char)((pb >> 8) & 0xff);
    }
    *(int4*)&W[(ra + r) * NB + rb + c0] = *(int4*)&oa[0];
    *(int4*)&W[(rb + r) * NB + ra + c0] = *(int4*)&ob[0];
}

// ---------------- kernel 3: fused fp8 128x128-tile GEMM + loss epilogue -----
// 2080 logical blocks (XCD-chunked, 2080 = 8*260):
//   b < 1024: cross S1 = Mf Pf^T, 32x32 grid.
//   b >= 1024: symmetric (Mf then Pf), upper-tri 528 each.
// 256 threads = 4 waves (2x2), wave tile 64x64, acc[4][4].
// No min-waves pin: at ~148 unified regs 3 blocks/CU remain eligible
// (2048/148 = 13.8 waves) without forcing an allocator squeeze (R15's
// 87MB WRITE anomaly). K loop: 16 tiles BK=64 fp8, THREE 16KB LDS buffers,
// depth-2, vmcnt(4), one barrier/step. Epilogue: 16KB fp8 Wsym tile.
__global__ __launch_bounds__(256) void mega_gemm(
        const unsigned char* __restrict__ Mf, const unsigned char* __restrict__ Pf,
        const unsigned char* __restrict__ Wg,
        float* __restrict__ rowsum1, float* __restrict__ colsum1,
        float* __restrict__ rowsum3, float* __restrict__ rowsum4,
        float* __restrict__ dots) {
    __shared__ char smem[49152] __attribute__((aligned(16)));

    int tid = threadIdx.x;
    int lane = tid & 63, w = tid >> 6;      // w: 0..3
    int wm = w >> 1, wn = w & 1;            // 2x2 wave grid
    int lr = lane & 15, lg = lane >> 4;

    // ---- block decode ----
    int b = (blockIdx.x & 7) * 260 + (blockIdx.x >> 3);
    int bi, bj, mode;
    const unsigned char *A, *Bm;
    if (b < 1024) {
        bi = b >> 5;
        bj = b & 31;
        A = Mf; Bm = Pf; mode = 0;
    } else {
        int s = b - 1024;
        int md = (s >= 528) ? 1 : 0;
        s -= md * 528;
        bi = 0;
        while (s >= 32 - bi) { s -= 32 - bi; ++bi; }
        bj = bi + s;
        A = md ? Pf : Mf; Bm = A;
        mode = 1 + md;
    }
    bool offdiag = (bi != bj);
    size_t rowBase = (size_t)bi * 128;
    size_t colBase = (size_t)bj * 128;
    float* rowTgt = (mode == 0) ? rowsum1 : ((mode == 1) ? rowsum3 : rowsum4);
    float* colTgt = (mode == 0) ? colsum1 : rowTgt;

    // ---- staging addresses: 64B fp8 rows, 4 lanes/row, pre-swizzled chunk --
    int sr = lane >> 2;                        // row 0..15 within 1KB unit
    int scs = (lane & 3) ^ (sr & 3) ^ ((sr >> 2) & 3);   // 16B chunk
    const unsigned char* gA = A + (rowBase + w * 32 + sr) * ND + scs * 16;
    const unsigned char* gB = Bm + (colBase + w * 32 + sr) * ND + scs * 16;

    f32x4 acc[4][4] = {};

    // per tile: A 128x64B (8KB) + B 128x64B (8KB); 4 x 1KB units per wave
#define STAGE(bufi, t) {                                                    \
        int k0_ = (t) * 64;                                                 \
        char* baseA_ = smem + (bufi) * 16384;                               \
        char* baseB_ = baseA_ + 8192;                                       \
        gload16(gA + k0_,                   baseA_ + (w * 2    ) * 1024);   \
        gload16(gA + (size_t)16 * ND + k0_, baseA_ + (w * 2 + 1) * 1024);   \
        gload16(gB + k0_,                   baseB_ + (w * 2    ) * 1024);   \
        gload16(gB + (size_t)16 * ND + k0_, baseB_ + (w * 2 + 1) * 1024);   \
    }
#define COMPUTE(bufi) {                                                     \
        const unsigned char* sA = (const unsigned char*)(smem + (bufi) * 16384); \
        const unsigned char* sB = sA + 8192;                                \
        int rx = (lr & 3) ^ ((lr >> 2) & 3);                                \
        _Pragma("unroll")                                                   \
        for (int ks = 0; ks < 2; ++ks) {                                    \
            int cp = (((ks * 2) + (lg >> 1)) ^ rx) * 16 + (lg & 1) * 8;     \
            long av[4], bv[4];                                              \
            _Pragma("unroll")                                               \
            for (int n = 0; n < 4; ++n)                                     \
                bv[n] = *(const long*)&sB[(wn * 64 + n * 16 + lr) * 64 + cp]; \
            _Pragma("unroll")                                               \
            for (int i = 0; i < 4; ++i)                                     \
                av[i] = *(const long*)&sA[(wm * 64 + i * 16 + lr) * 64 + cp]; \
            _Pragma("unroll")                                               \
            for (int i = 0; i < 4; ++i)                                     \
                _Pragma("unroll")                                           \
                for (int n = 0; n < 4; ++n)                                 \
                    acc[i][n] = __builtin_amdgcn_mfma_f32_16x16x32_fp8_fp8( \
                        av[i], bv[n], acc[i][n], 0, 0, 0);                  \
        }                                                                   \
    }
#define BAR __builtin_amdgcn_s_barrier()

    // depth-2 pipeline over 3 buffers; buffer t%3 holds tile t. 4 loads/step.
    STAGE(0, 0); STAGE(1, 1);                       // 8 outstanding
    asm volatile("s_waitcnt vmcnt(4)" ::: "memory"); BAR;   // tile 0 ready
    for (int t = 0; t < 14; ++t) {
        STAGE((t + 2) % 3, t + 2);    // overwrites buf computed at t-1 (safe)
        COMPUTE(t % 3);
        asm volatile("s_waitcnt vmcnt(4)" ::: "memory"); BAR;  // tile t+1 ready
    }
    COMPUTE(14 % 3);
    asm volatile("s_waitcnt vmcnt(0)" ::: "memory"); BAR;
    COMPUTE(15 % 3);
    __syncthreads();
#undef STAGE
#undef COMPUTE
#undef BAR

    // ---- epilogue: single fp8 Wsym tile (128 rows x 128 cols = 16KB) ----
    unsigned char* wl = (unsigned char*)smem;
    float d1 = 0.f;
    float cexp[4] = {0.f, 0.f, 0.f, 0.f};

    // 16 x 1KB units (8 rows of 128B each); 4 units per wave, swizzled
#pragma unroll
    for (int c = 0; c < 4; ++c) {
        int q = w * 4 + c;                          // 0..15
        int sw = 8 * q + (lane >> 3);               // W row 0..127
        int gchunk = (lane & 7) ^ (sw & 7);         // source pre-swizzle
        gload16(Wg + (rowBase + sw) * (size_t)NB + colBase + gchunk * 16,
                smem + q * 1024);
    }
    __syncthreads();
#pragma unroll
    for (int m = 0; m < 4; ++m) {
        float rexp[4] = {0.f, 0.f, 0.f, 0.f};
#pragma unroll
        for (int n = 0; n < 4; ++n) {
            int jl = wn * 64 + n * 16 + lr;         // 0..127
#pragma unroll
            for (int r = 0; r < 4; ++r) {
                int rl = wm * 64 + m * 16 + lg * 4 + r;   // 0..127
                float sim = acc[m][n][r] * INV_T;
                float e = __expf(sim - INV_T);
                rexp[r] += e;
                cexp[n] += e;
                int ck = (jl >> 4) ^ (rl & 7);
                d1 += fp82f(wl[rl * 128 + ck * 16 + (jl & 15)]) * sim;
            }
        }
#pragma unroll
        for (int r = 0; r < 4; ++r) {
            float v = rexp[r];
            v += __shfl_xor(v, 1); v += __shfl_xor(v, 2);
            v += __shfl_xor(v, 4); v += __shfl_xor(v, 8);
            if (lr == 0)
                atomicAdd(&rowTgt[rowBase + wm * 64 + m * 16 + lg * 4 + r], v);
        }
    }

    // col-exp sums: cross always; symmetric only for offdiag tiles
    if (mode == 0 || offdiag) {
#pragma unroll
        for (int n = 0; n < 4; ++n) {
            float v = cexp[n];
            v += __shfl_xor(v, 16); v += __shfl_xor(v, 32);
            if (lg == 0)
                atomicAdd(&colTgt[colBase + wn * 64 + n * 16 + lr], v);
        }
    }

    // weighted dot: Wsym covers (i,j)+(j,i). diag tile counts half.
    float dtot = (mode != 0 && !offdiag) ? 0.5f * d1 : d1;
    for (int off = 32; off; off >>= 1) dtot += __shfl_xor(dtot, off);
    if (lane == 0) {
        if (mode == 0) atomicAdd(&dots[0], dtot);
        else           atomicAdd(&dots[1 + mode], dtot);
    }
}

// ---------------- kernel 4: finalize --------------------------------------
__global__ __launch_bounds__(256) void finalize_kernel(
        const float* __restrict__ rowsum1, const float* __restrict__ colsum1,
        const float* __restrict__ rowsum3, const float* __restrict__ rowsum4,
        const float* __restrict__ flag, const float* __restrict__ dots,
        float* __restrict__ out) {
    int tid = threadIdx.x;
    float l = 0.f;
    for (int i = tid; i < NB; i += 256) {
        if (flag[i] != 0.f) {
            l += 4.f * INV_T + logf(rowsum1[i]) + logf(colsum1[i]) +
                 logf(rowsum3[i]) + logf(rowsum4[i]);
        }
    }
    for (int off = 32; off; off >>= 1) l += __shfl_down(l, off);
    __shared__ float red[4];
    int lane = tid & 63, w = tid >> 6;
    if (lane == 0) red[w] = l;
    __syncthreads();
    if (tid == 0) {
        float L = red[0] + red[1] + red[2] + red[3];
        float dt = dots[0] + dots[1] + dots[2] + dots[3];
        out[0] = (L - dt) / (4.0f * (float)NB);
    }
}

extern "C" void kernel_launch(void* const* d_in, const int* in_sizes, int n_in,
                              void* d_out, int out_size, void* d_ws, size_t ws_size,
                              hipStream_t stream) {
    const float* M = (const float*)d_in[0];
    const float* P = (const float*)d_in[1];
    const int* labels = (const int*)d_in[2];
    const int* sm = (const int*)d_in[3];
    const int* sp = (const int*)d_in[4];
    const float* cs = (const float*)d_in[5];
    float* out = (float*)d_out;

    char* ws = (char*)d_ws;
    unsigned char* Mf = (unsigned char*)ws;                                // 4 MB
    unsigned char* Pf = (unsigned char*)(ws + (size_t)4 * 1024 * 1024);    // 4 MB
    unsigned char* W = (unsigned char*)(ws + (size_t)16 * 1024 * 1024);    // 16 MB
    char* p = ws + (size_t)48 * 1024 * 1024;
    int* code = (int*)p;        p += 16384;
    float* flag = (float*)p;    p += 16384;
    float* rowsum1 = (float*)p; p += 16384;
    float* colsum1 = (float*)p; p += 16384;
    float* rowsum3 = (float*)p; p += 16384;
    float* rowsum4 = (float*)p; p += 16384;
    float* dots = (float*)p;

    hipMemsetAsync(rowsum1, 0, 4 * 16384 + 256, stream);

    norm_kernel<<<2 * NB, 256, 0, stream>>>(M, P, Mf, Pf);
    key_kernel<<<NB / 256, 256, 0, stream>>>(labels, sm, sp, code);
    rowsumw_kernel<<<NB, 256, 0, stream>>>(cs, code, W, flag);
    symw_kernel<<<2080, 256, 0, stream>>>(W);

    mega_gemm<<<2080, 256, 0, stream>>>(Mf, Pf, W, rowsum1, colsum1,
                                        rowsum3, rowsum4, dots);

    finalize_kernel<<<1, 256, 0, stream>>>(rowsum1, colsum1, rowsum3, rowsum4,
                                           flag, dots, out);
}

// Round 17
// 194.217 us; speedup vs baseline: 1.0978x; 1.0978x over previous
//
#include <hip/hip_runtime.h>
#include <hip/hip_bf16.h>
#include <hip/hip_fp8.h>
#include <math.h>

typedef __attribute__((ext_vector_type(4))) float f32x4;

#define NB 4096
#define ND 1024
#define INV_T 14.2857142857142857f   // 1/0.07

__device__ inline float fp82f(unsigned char b) {
    __hip_fp8_e4m3 h; h.__x = b;
    return (float)h;
}
__device__ inline void gload16(const void* g, void* l) {
    __builtin_amdgcn_global_load_lds(
        (const __attribute__((address_space(1))) void*)g,
        (__attribute__((address_space(3))) void*)l, 16, 0, 0);
}

// ---------------- kernel 0: L2-normalize rows, cast to fp8 e4m3 -------------
__global__ __launch_bounds__(256) void norm_kernel(
        const float* __restrict__ M, const float* __restrict__ P,
        unsigned char* __restrict__ Mf, unsigned char* __restrict__ Pf) {
    int row = blockIdx.x & (NB - 1);
    const float* src = (blockIdx.x < NB) ? M : P;
    unsigned char* dst = (blockIdx.x < NB) ? Mf : Pf;
    int tid = threadIdx.x;
    float4 v = ((const float4*)(src + (size_t)row * ND))[tid];
    float ss = v.x * v.x + v.y * v.y + v.z * v.z + v.w * v.w;
    for (int off = 32; off; off >>= 1) ss += __shfl_down(ss, off);
    __shared__ float red[4];
    int lane = tid & 63, w = tid >> 6;
    if (lane == 0) red[w] = ss;
    __syncthreads();
    float rn = rsqrtf(red[0] + red[1] + red[2] + red[3]);
    int p = __builtin_amdgcn_cvt_pk_fp8_f32(v.x * rn, v.y * rn, 0, false);
    p = __builtin_amdgcn_cvt_pk_fp8_f32(v.z * rn, v.w * rn, p, true);
    ((int*)dst)[row * 256 + tid] = p;
}

// ---------------- kernel 1: per-row mask codes ------------------------------
__global__ __launch_bounds__(256) void key_kernel(
        const int* __restrict__ labels, const int* __restrict__ sm,
        const int* __restrict__ sp, int* __restrict__ code) {
    int i = blockIdx.x * 256 + threadIdx.x;
    if (i < NB) {
        int l = labels[i];
        code[i] = (l == 0) ? 0x40000000 : (1 + l + (sm[i] << 8) + (sp[i] << 16));
    }
}

// ------- kernel 2: fused row-sum + normalized masked weight matrix (fp8) ----
__global__ __launch_bounds__(256) void rowsumw_kernel(
        const float* __restrict__ cs, const int* __restrict__ code,
        unsigned char* __restrict__ W, float* __restrict__ flag) {
    int i = blockIdx.x;
    int ci = code[i];
    int tid = threadIdx.x;
    const float4* row = (const float4*)(cs + (size_t)i * NB);
    const int4* c4 = (const int4*)code;
    float4 v[4];
    int4 cj[4];
    float s = 0.f;
#pragma unroll
    for (int k = 0; k < 4; ++k) {
        int t = tid + k * 256;
        v[k] = row[t];
        cj[k] = c4[t];
        int j = t * 4;
        if (cj[k].x == ci && j + 0 != i) s += v[k].x;
        if (cj[k].y == ci && j + 1 != i) s += v[k].y;
        if (cj[k].z == ci && j + 2 != i) s += v[k].z;
        if (cj[k].w == ci && j + 3 != i) s += v[k].w;
    }
    for (int off = 1; off < 64; off <<= 1) s += __shfl_xor(s, off);
    __shared__ float red[4];
    int lane = tid & 63, w = tid >> 6;
    if (lane == 0) red[w] = s;
    __syncthreads();
    float tot = red[0] + red[1] + red[2] + red[3];
    float inv = (tot > 0.f) ? 1.f / tot : 0.f;
#pragma unroll
    for (int k = 0; k < 4; ++k) {
        int t = tid + k * 256;
        int j = t * 4;
        float f0 = (cj[k].x == ci && j + 0 != i) ? v[k].x * inv : 0.f;
        float f1 = (cj[k].y == ci && j + 1 != i) ? v[k].y * inv : 0.f;
        float f2 = (cj[k].z == ci && j + 2 != i) ? v[k].z * inv : 0.f;
        float f3 = (cj[k].w == ci && j + 3 != i) ? v[k].w * inv : 0.f;
        int p = __builtin_amdgcn_cvt_pk_fp8_f32(f0, f1, 0, false);
        p = __builtin_amdgcn_cvt_pk_fp8_f32(f2, f3, p, true);
        ((int*)W)[((size_t)i * NB + j) >> 2] = p;
    }
    if (tid == 0) flag[i] = (tot > 0.f) ? 1.f : 0.f;
}

// ------- kernel 2b: in-place symmetrize W -> Wsym = W + W^T (fp8) -----------
__global__ __launch_bounds__(256) void symw_kernel(unsigned char* __restrict__ W) {
    __shared__ unsigned char Ta[64][80], Tb[64][80];
    int b = blockIdx.x;
    int ti = 0, t = b;
    while (t >= 64 - ti) { t -= 64 - ti; ++ti; }
    int tj = ti + t;
    size_t ra = (size_t)ti * 64, rb = (size_t)tj * 64;
    int tid = threadIdx.x;
    int r = tid >> 2, c0 = (tid & 3) * 16;
    int4 a0 = *(const int4*)&W[(ra + r) * NB + rb + c0];
    int4 b0 = *(const int4*)&W[(rb + r) * NB + ra + c0];
    *(int4*)&Ta[r][c0] = a0;
    *(int4*)&Tb[r][c0] = b0;
    __syncthreads();
    unsigned char oa[16], ob[16];
#pragma unroll
    for (int c = 0; c < 16; c += 2) {
        int cc = c0 + c;
        float a_lo = fp82f(Ta[r][cc])     + fp82f(Tb[cc][r]);
        float a_hi = fp82f(Ta[r][cc + 1]) + fp82f(Tb[cc + 1][r]);
        float b_lo = fp82f(Tb[r][cc])     + fp82f(Ta[cc][r]);
        float b_hi = fp82f(Tb[r][cc + 1]) + fp82f(Ta[cc + 1][r]);
        int pa = __builtin_amdgcn_cvt_pk_fp8_f32(a_lo, a_hi, 0, false);
        int pb = __builtin_amdgcn_cvt_pk_fp8_f32(b_lo, b_hi, 0, false);
        oa[c] = (unsigned char)(pa & 0xff); oa[c + 1] = (unsigned char)((pa >> 8) & 0xff);
        ob[c] = (unsigned char)(pb & 0xff); ob[c + 1] = (unsigned char)((pb >> 8) & 0xff);
    }
    *(int4*)&W[(ra + r) * NB + rb + c0] = *(int4*)&oa[0];
    *(int4*)&W[(rb + r) * NB + ra + c0] = *(int4*)&ob[0];
}

// ---------------- kernel 3: fused fp8 128x128-tile GEMM + loss epilogue -----
// 2080 logical blocks (XCD-chunked, 2080 = 8*260):
//   b < 1024: cross S1 = Mf Pf^T, 4x4-SUPERTILED 32x32 grid: 16-block groups
//             touch 4 A-panels + 4 B-panels = 1MB << 4MB L2 (cuts the 5.6x
//             L2-miss over-fetch measured in R16).
//   b >= 1024: symmetric (Mf then Pf), upper-tri 528 each (A-panel runs).
// 256 threads = 4 waves (2x2), wave tile 64x64, acc[4][4].
// (256,3) pin restored: R15/R16 A/B showed pin(84 arch + 41-reg L2-resident
// spill, 2-3 blk/CU) beats unpinned (152 arch, 2 blk/CU): 159 vs 177 us.
// K loop: 16 tiles BK=64 fp8, THREE 16KB LDS buffers, depth-2, vmcnt(4).
__global__ __launch_bounds__(256, 3) void mega_gemm(
        const unsigned char* __restrict__ Mf, const unsigned char* __restrict__ Pf,
        const unsigned char* __restrict__ Wg,
        float* __restrict__ rowsum1, float* __restrict__ colsum1,
        float* __restrict__ rowsum3, float* __restrict__ rowsum4,
        float* __restrict__ dots) {
    __shared__ char smem[49152] __attribute__((aligned(16)));

    int tid = threadIdx.x;
    int lane = tid & 63, w = tid >> 6;      // w: 0..3
    int wm = w >> 1, wn = w & 1;            // 2x2 wave grid
    int lr = lane & 15, lg = lane >> 4;

    // ---- block decode ----
    int b = (blockIdx.x & 7) * 260 + (blockIdx.x >> 3);
    int bi, bj, mode;
    const unsigned char *A, *Bm;
    if (b < 1024) {
        int st = b >> 4;                    // supertile 0..63 (8 rows x 8 cols)
        int sb = b & 15;                    // 4x4 within supertile
        bi = (st >> 3) * 4 + (sb >> 2);
        bj = (st & 7) * 4 + (sb & 3);
        A = Mf; Bm = Pf; mode = 0;
    } else {
        int s = b - 1024;
        int md = (s >= 528) ? 1 : 0;
        s -= md * 528;
        bi = 0;
        while (s >= 32 - bi) { s -= 32 - bi; ++bi; }
        bj = bi + s;
        A = md ? Pf : Mf; Bm = A;
        mode = 1 + md;
    }
    bool offdiag = (bi != bj);
    size_t rowBase = (size_t)bi * 128;
    size_t colBase = (size_t)bj * 128;
    float* rowTgt = (mode == 0) ? rowsum1 : ((mode == 1) ? rowsum3 : rowsum4);
    float* colTgt = (mode == 0) ? colsum1 : rowTgt;

    // ---- staging addresses: 64B fp8 rows, 4 lanes/row, pre-swizzled chunk --
    int sr = lane >> 2;                        // row 0..15 within 1KB unit
    int scs = (lane & 3) ^ (sr & 3) ^ ((sr >> 2) & 3);   // 16B chunk
    const unsigned char* gA = A + (rowBase + w * 32 + sr) * ND + scs * 16;
    const unsigned char* gB = Bm + (colBase + w * 32 + sr) * ND + scs * 16;

    f32x4 acc[4][4] = {};

    // per tile: A 128x64B (8KB) + B 128x64B (8KB); 4 x 1KB units per wave
#define STAGE(bufi, t) {                                                    \
        int k0_ = (t) * 64;                                                 \
        char* baseA_ = smem + (bufi) * 16384;                               \
        char* baseB_ = baseA_ + 8192;                                       \
        gload16(gA + k0_,                   baseA_ + (w * 2    ) * 1024);   \
        gload16(gA + (size_t)16 * ND + k0_, baseA_ + (w * 2 + 1) * 1024);   \
        gload16(gB + k0_,                   baseB_ + (w * 2    ) * 1024);   \
        gload16(gB + (size_t)16 * ND + k0_, baseB_ + (w * 2 + 1) * 1024);   \
    }
#define COMPUTE(bufi) {                                                     \
        const unsigned char* sA = (const unsigned char*)(smem + (bufi) * 16384); \
        const unsigned char* sB = sA + 8192;                                \
        int rx = (lr & 3) ^ ((lr >> 2) & 3);                                \
        _Pragma("unroll")                                                   \
        for (int ks = 0; ks < 2; ++ks) {                                    \
            int cp = (((ks * 2) + (lg >> 1)) ^ rx) * 16 + (lg & 1) * 8;     \
            long av[4], bv[4];                                              \
            _Pragma("unroll")                                               \
            for (int n = 0; n < 4; ++n)                                     \
                bv[n] = *(const long*)&sB[(wn * 64 + n * 16 + lr) * 64 + cp]; \
            _Pragma("unroll")                                               \
            for (int i = 0; i < 4; ++i)                                     \
                av[i] = *(const long*)&sA[(wm * 64 + i * 16 + lr) * 64 + cp]; \
            _Pragma("unroll")                                               \
            for (int i = 0; i < 4; ++i)                                     \
                _Pragma("unroll")                                           \
                for (int n = 0; n < 4; ++n)                                 \
                    acc[i][n] = __builtin_amdgcn_mfma_f32_16x16x32_fp8_fp8( \
                        av[i], bv[n], acc[i][n], 0, 0, 0);                  \
        }                                                                   \
    }
#define BAR __builtin_amdgcn_s_barrier()

    // depth-2 pipeline over 3 buffers; buffer t%3 holds tile t. 4 loads/step.
    STAGE(0, 0); STAGE(1, 1);                       // 8 outstanding
    asm volatile("s_waitcnt vmcnt(4)" ::: "memory"); BAR;   // tile 0 ready
    for (int t = 0; t < 14; ++t) {
        STAGE((t + 2) % 3, t + 2);    // overwrites buf computed at t-1 (safe)
        COMPUTE(t % 3);
        asm volatile("s_waitcnt vmcnt(4)" ::: "memory"); BAR;  // tile t+1 ready
    }
    COMPUTE(14 % 3);
    asm volatile("s_waitcnt vmcnt(0)" ::: "memory"); BAR;
    COMPUTE(15 % 3);
    __syncthreads();
#undef STAGE
#undef COMPUTE
#undef BAR

    // ---- epilogue: single fp8 Wsym tile (128 rows x 128 cols = 16KB) ----
    unsigned char* wl = (unsigned char*)smem;
    float d1 = 0.f;
    float cexp[4] = {0.f, 0.f, 0.f, 0.f};

    // 16 x 1KB units (8 rows of 128B each); 4 units per wave, swizzled
#pragma unroll
    for (int c = 0; c < 4; ++c) {
        int q = w * 4 + c;                          // 0..15
        int sw = 8 * q + (lane >> 3);               // W row 0..127
        int gchunk = (lane & 7) ^ (sw & 7);         // source pre-swizzle
        gload16(Wg + (rowBase + sw) * (size_t)NB + colBase + gchunk * 16,
                smem + q * 1024);
    }
    __syncthreads();
#pragma unroll
    for (int m = 0; m < 4; ++m) {
        float rexp[4] = {0.f, 0.f, 0.f, 0.f};
#pragma unroll
        for (int n = 0; n < 4; ++n) {
            int jl = wn * 64 + n * 16 + lr;         // 0..127
#pragma unroll
            for (int r = 0; r < 4; ++r) {
                int rl = wm * 64 + m * 16 + lg * 4 + r;   // 0..127
                float sim = acc[m][n][r] * INV_T;
                float e = __expf(sim - INV_T);
                rexp[r] += e;
                cexp[n] += e;
                int ck = (jl >> 4) ^ (rl & 7);
                d1 += fp82f(wl[rl * 128 + ck * 16 + (jl & 15)]) * sim;
            }
        }
#pragma unroll
        for (int r = 0; r < 4; ++r) {
            float v = rexp[r];
            v += __shfl_xor(v, 1); v += __shfl_xor(v, 2);
            v += __shfl_xor(v, 4); v += __shfl_xor(v, 8);
            if (lr == 0)
                atomicAdd(&rowTgt[rowBase + wm * 64 + m * 16 + lg * 4 + r], v);
        }
    }

    // col-exp sums: cross always; symmetric only for offdiag tiles
    if (mode == 0 || offdiag) {
#pragma unroll
        for (int n = 0; n < 4; ++n) {
            float v = cexp[n];
            v += __shfl_xor(v, 16); v += __shfl_xor(v, 32);
            if (lg == 0)
                atomicAdd(&colTgt[colBase + wn * 64 + n * 16 + lr], v);
        }
    }

    // weighted dot: Wsym covers (i,j)+(j,i). diag tile counts half.
    float dtot = (mode != 0 && !offdiag) ? 0.5f * d1 : d1;
    for (int off = 32; off; off >>= 1) dtot += __shfl_xor(dtot, off);
    if (lane == 0) {
        if (mode == 0) atomicAdd(&dots[0], dtot);
        else           atomicAdd(&dots[1 + mode], dtot);
    }
}

// ---------------- kernel 4: finalize --------------------------------------
__global__ __launch_bounds__(256) void finalize_kernel(
        const float* __restrict__ rowsum1, const float* __restrict__ colsum1,
        const float* __restrict__ rowsum3, const float* __restrict__ rowsum4,
        const float* __restrict__ flag, const float* __restrict__ dots,
        float* __restrict__ out) {
    int tid = threadIdx.x;
    float l = 0.f;
    for (int i = tid; i < NB; i += 256) {
        if (flag[i] != 0.f) {
            l += 4.f * INV_T + logf(rowsum1[i]) + logf(colsum1[i]) +
                 logf(rowsum3[i]) + logf(rowsum4[i]);
        }
    }
    for (int off = 32; off; off >>= 1) l += __shfl_down(l, off);
    __shared__ float red[4];
    int lane = tid & 63, w = tid >> 6;
    if (lane == 0) red[w] = l;
    __syncthreads();
    if (tid == 0) {
        float L = red[0] + red[1] + red[2] + red[3];
        float dt = dots[0] + dots[1] + dots[2] + dots[3];
        out[0] = (L - dt) / (4.0f * (float)NB);
    }
}

extern "C" void kernel_launch(void* const* d_in, const int* in_sizes, int n_in,
                              void* d_out, int out_size, void* d_ws, size_t ws_size,
                              hipStream_t stream) {
    const float* M = (const float*)d_in[0];
    const float* P = (const float*)d_in[1];
    const int* labels = (const int*)d_in[2];
    const int* sm = (const int*)d_in[3];
    const int* sp = (const int*)d_in[4];
    const float* cs = (const float*)d_in[5];
    float* out = (float*)d_out;

    char* ws = (char*)d_ws;
    unsigned char* Mf = (unsigned char*)ws;                                // 4 MB
    unsigned char* Pf = (unsigned char*)(ws + (size_t)4 * 1024 * 1024);    // 4 MB
    unsigned char* W = (unsigned char*)(ws + (size_t)16 * 1024 * 1024);    // 16 MB
    char* p = ws + (size_t)48 * 1024 * 1024;
    int* code = (int*)p;        p += 16384;
    float* flag = (float*)p;    p += 16384;
    float* rowsum1 = (float*)p; p += 16384;
    float* colsum1 = (float*)p; p += 16384;
    float* rowsum3 = (float*)p; p += 16384;
    float* rowsum4 = (float*)p; p += 16384;
    float* dots = (float*)p;

    hipMemsetAsync(rowsum1, 0, 4 * 16384 + 256, stream);

    norm_kernel<<<2 * NB, 256, 0, stream>>>(M, P, Mf, Pf);
    key_kernel<<<NB / 256, 256, 0, stream>>>(labels, sm, sp, code);
    rowsumw_kernel<<<NB, 256, 0, stream>>>(cs, code, W, flag);
    symw_kernel<<<2080, 256, 0, stream>>>(W);

    mega_gemm<<<2080, 256, 0, stream>>>(Mf, Pf, W, rowsum1, colsum1,
                                        rowsum3, rowsum4, dots);

    finalize_kernel<<<1, 256, 0, stream>>>(rowsum1, colsum1, rowsum3, rowsum4,
                                           flag, dots, out);
}

// Round 18
// 194.161 us; speedup vs baseline: 1.0981x; 1.0003x over previous
//
#include <hip/hip_runtime.h>
#include <hip/hip_bf16.h>
#include <hip/hip_fp8.h>
#include <math.h>

typedef __attribute__((ext_vector_type(4))) float f32x4;

#define NB 4096
#define ND 1024
#define INV_T 14.2857142857142857f   // 1/0.07

__device__ inline float fp82f(unsigned char b) {
    __hip_fp8_e4m3 h; h.__x = b;
    return (float)h;
}
__device__ inline void gload16(const void* g, void* l) {
    __builtin_amdgcn_global_load_lds(
        (const __attribute__((address_space(1))) void*)g,
        (__attribute__((address_space(3))) void*)l, 16, 0, 0);
}

// ---------------- kernel 0: L2-normalize rows, cast to fp8 e4m3 -------------
__global__ __launch_bounds__(256) void norm_kernel(
        const float* __restrict__ M, const float* __restrict__ P,
        unsigned char* __restrict__ Mf, unsigned char* __restrict__ Pf) {
    int row = blockIdx.x & (NB - 1);
    const float* src = (blockIdx.x < NB) ? M : P;
    unsigned char* dst = (blockIdx.x < NB) ? Mf : Pf;
    int tid = threadIdx.x;
    float4 v = ((const float4*)(src + (size_t)row * ND))[tid];
    float ss = v.x * v.x + v.y * v.y + v.z * v.z + v.w * v.w;
    for (int off = 32; off; off >>= 1) ss += __shfl_down(ss, off);
    __shared__ float red[4];
    int lane = tid & 63, w = tid >> 6;
    if (lane == 0) red[w] = ss;
    __syncthreads();
    float rn = rsqrtf(red[0] + red[1] + red[2] + red[3]);
    int p = __builtin_amdgcn_cvt_pk_fp8_f32(v.x * rn, v.y * rn, 0, false);
    p = __builtin_amdgcn_cvt_pk_fp8_f32(v.z * rn, v.w * rn, p, true);
    ((int*)dst)[row * 256 + tid] = p;
}

// ---------------- kernel 1: per-row mask codes ------------------------------
__global__ __launch_bounds__(256) void key_kernel(
        const int* __restrict__ labels, const int* __restrict__ sm,
        const int* __restrict__ sp, int* __restrict__ code) {
    int i = blockIdx.x * 256 + threadIdx.x;
    if (i < NB) {
        int l = labels[i];
        code[i] = (l == 0) ? 0x40000000 : (1 + l + (sm[i] << 8) + (sp[i] << 16));
    }
}

// ------- kernel 2: fused row-sum + normalized masked weight matrix (fp8) ----
__global__ __launch_bounds__(256) void rowsumw_kernel(
        const float* __restrict__ cs, const int* __restrict__ code,
        unsigned char* __restrict__ W, float* __restrict__ flag) {
    int i = blockIdx.x;
    int ci = code[i];
    int tid = threadIdx.x;
    const float4* row = (const float4*)(cs + (size_t)i * NB);
    const int4* c4 = (const int4*)code;
    float4 v[4];
    int4 cj[4];
    float s = 0.f;
#pragma unroll
    for (int k = 0; k < 4; ++k) {
        int t = tid + k * 256;
        v[k] = row[t];
        cj[k] = c4[t];
        int j = t * 4;
        if (cj[k].x == ci && j + 0 != i) s += v[k].x;
        if (cj[k].y == ci && j + 1 != i) s += v[k].y;
        if (cj[k].z == ci && j + 2 != i) s += v[k].z;
        if (cj[k].w == ci && j + 3 != i) s += v[k].w;
    }
    for (int off = 1; off < 64; off <<= 1) s += __shfl_xor(s, off);
    __shared__ float red[4];
    int lane = tid & 63, w = tid >> 6;
    if (lane == 0) red[w] = s;
    __syncthreads();
    float tot = red[0] + red[1] + red[2] + red[3];
    float inv = (tot > 0.f) ? 1.f / tot : 0.f;
#pragma unroll
    for (int k = 0; k < 4; ++k) {
        int t = tid + k * 256;
        int j = t * 4;
        float f0 = (cj[k].x == ci && j + 0 != i) ? v[k].x * inv : 0.f;
        float f1 = (cj[k].y == ci && j + 1 != i) ? v[k].y * inv : 0.f;
        float f2 = (cj[k].z == ci && j + 2 != i) ? v[k].z * inv : 0.f;
        float f3 = (cj[k].w == ci && j + 3 != i) ? v[k].w * inv : 0.f;
        int p = __builtin_amdgcn_cvt_pk_fp8_f32(f0, f1, 0, false);
        p = __builtin_amdgcn_cvt_pk_fp8_f32(f2, f3, p, true);
        ((int*)W)[((size_t)i * NB + j) >> 2] = p;
    }
    if (tid == 0) flag[i] = (tot > 0.f) ? 1.f : 0.f;
}

// ---------------- kernel 3: fused fp8 128x128-tile GEMM + loss epilogue -----
// 2080 logical blocks (XCD-chunked, 2080 = 8*260):
//   b < 1024: cross S1 = Mf Pf^T, 4x4-supertiled 32x32 grid (L2 locality).
//   b >= 1024: symmetric (Mf then Pf), upper-tri 528 each.
// 256 threads = 4 waves (2x2), wave tile 64x64, acc[4][4], (256,3) pin.
// Register diet vs R17 (goal: no spill at 3 blk/CU): ks-loop unroll(1)
// (halves live MFMA operands), single output base pointer.
// Epilogue: W[i][j] AND W[j][i] fp8 tiles (symw prepass fused away; f32 add),
// PREFETCHED into freed K-loop buffers during the last two compute steps.
__global__ __launch_bounds__(256, 3) void mega_gemm(
        const unsigned char* __restrict__ Mf, const unsigned char* __restrict__ Pf,
        const unsigned char* __restrict__ Wg,
        float* __restrict__ outs) {
    __shared__ char smem[49152] __attribute__((aligned(16)));

    int tid = threadIdx.x;
    int lane = tid & 63, w = tid >> 6;      // w: 0..3
    int wm = w >> 1, wn = w & 1;            // 2x2 wave grid
    int lr = lane & 15, lg = lane >> 4;

    // ---- block decode ----
    int b = (blockIdx.x & 7) * 260 + (blockIdx.x >> 3);
    int bi, bj, mode;
    const unsigned char *A, *Bm;
    if (b < 1024) {
        int st = b >> 4;                    // supertile 0..63 (8 rows x 8 cols)
        int sb = b & 15;                    // 4x4 within supertile
        bi = (st >> 3) * 4 + (sb >> 2);
        bj = (st & 7) * 4 + (sb & 3);
        A = Mf; Bm = Pf; mode = 0;
    } else {
        int s = b - 1024;
        int md = (s >= 528) ? 1 : 0;
        s -= md * 528;
        bi = 0;
        while (s >= 32 - bi) { s -= 32 - bi; ++bi; }
        bj = bi + s;
        A = md ? Pf : Mf; Bm = A;
        mode = 1 + md;
    }
    bool offdiag = (bi != bj);
    size_t rowBase = (size_t)bi * 128;
    size_t colBase = (size_t)bj * 128;
    bool needW2 = (rowBase != colBase);
    float* rowTgt = outs + ((mode == 0) ? 0 : (mode == 1) ? 8192 : 12288);
    float* colTgt = (mode == 0) ? (outs + 4096) : rowTgt;

    // ---- staging addresses: 64B fp8 rows, 4 lanes/row, pre-swizzled chunk --
    int sr = lane >> 2;                        // row 0..15 within 1KB unit
    int scs = (lane & 3) ^ (sr & 3) ^ ((sr >> 2) & 3);   // 16B chunk
    const unsigned char* gA = A + (rowBase + w * 32 + sr) * ND + scs * 16;
    const unsigned char* gB = Bm + (colBase + w * 32 + sr) * ND + scs * 16;

    f32x4 acc[4][4] = {};

    // per tile: A 128x64B (8KB) + B 128x64B (8KB); 4 x 1KB units per wave
#define STAGE(bufi, t) {                                                    \
        int k0_ = (t) * 64;                                                 \
        char* baseA_ = smem + (bufi) * 16384;                               \
        char* baseB_ = baseA_ + 8192;                                       \
        gload16(gA + k0_,                   baseA_ + (w * 2    ) * 1024);   \
        gload16(gA + (size_t)16 * ND + k0_, baseA_ + (w * 2 + 1) * 1024);   \
        gload16(gB + k0_,                   baseB_ + (w * 2    ) * 1024);   \
        gload16(gB + (size_t)16 * ND + k0_, baseB_ + (w * 2 + 1) * 1024);   \
    }
// W-tile staging: 16KB = 128 rows x 128B, 4 x 1KB units per wave, swizzled
#define STAGEW(dst, rbase, cbase) {                                         \
        _Pragma("unroll")                                                   \
        for (int c = 0; c < 4; ++c) {                                       \
            int q_ = w * 4 + c;                                             \
            int sw_ = 8 * q_ + (lane >> 3);                                 \
            int gch_ = (lane & 7) ^ (sw_ & 7);                              \
            gload16(Wg + ((rbase) + sw_) * (size_t)NB + (cbase) + gch_ * 16,\
                    (dst) + q_ * 1024);                                     \
        }                                                                   \
    }
#define COMPUTE(bufi) {                                                     \
        const unsigned char* sA = (const unsigned char*)(smem + (bufi) * 16384); \
        const unsigned char* sB = sA + 8192;                                \
        int rx = (lr & 3) ^ ((lr >> 2) & 3);                                \
        _Pragma("unroll 1")                                                 \
        for (int ks = 0; ks < 2; ++ks) {                                    \
            int cp = (((ks * 2) + (lg >> 1)) ^ rx) * 16 + (lg & 1) * 8;     \
            long av[4], bv[4];                                              \
            _Pragma("unroll")                                               \
            for (int n = 0; n < 4; ++n)                                     \
                bv[n] = *(const long*)&sB[(wn * 64 + n * 16 + lr) * 64 + cp]; \
            _Pragma("unroll")                                               \
            for (int i = 0; i < 4; ++i)                                     \
                av[i] = *(const long*)&sA[(wm * 64 + i * 16 + lr) * 64 + cp]; \
            _Pragma("unroll")                                               \
            for (int i = 0; i < 4; ++i)                                     \
                _Pragma("unroll")                                           \
                for (int n = 0; n < 4; ++n)                                 \
                    acc[i][n] = __builtin_amdgcn_mfma_f32_16x16x32_fp8_fp8( \
                        av[i], bv[n], acc[i][n], 0, 0, 0);                  \
        }                                                                   \
    }
#define BAR __builtin_amdgcn_s_barrier()

    // depth-2 pipeline over 3 buffers; buffer t%3 holds tile t. 4 loads/step.
    STAGE(0, 0); STAGE(1, 1);                       // 8 outstanding
    asm volatile("s_waitcnt vmcnt(4)" ::: "memory"); BAR;   // tile 0 ready
    for (int t = 0; t < 14; ++t) {
        STAGE((t + 2) % 3, t + 2);    // overwrites buf computed at t-1 (safe)
        COMPUTE(t % 3);
        asm volatile("s_waitcnt vmcnt(4)" ::: "memory"); BAR;  // tile t+1 ready
    }
    // tail with W-tile prefetch into freed buffers:
    STAGEW(smem + 16384, rowBase, colBase);         // buf1 (tile 13) is free
    COMPUTE(2);                                     // tile 14
    BAR;                                            // all waves done with buf2
    if (needW2) STAGEW(smem + 32768, colBase, rowBase);   // buf2
    asm volatile("s_waitcnt vmcnt(0)" ::: "memory"); BAR;   // tile15 + W ready
    COMPUTE(0);                                     // tile 15
#undef STAGE
#undef STAGEW
#undef COMPUTE
#undef BAR

    // ---- epilogue: W1 = W[i-tile][j-tile], W2 = W[j-tile][i-tile] ----
    const unsigned char* wl1 = (const unsigned char*)smem + 16384;
    const unsigned char* wl2 = needW2 ? (const unsigned char*)smem + 32768 : wl1;
    float d1 = 0.f;
    float cexp[4] = {0.f, 0.f, 0.f, 0.f};

#pragma unroll
    for (int m = 0; m < 4; ++m) {
        float rexp[4] = {0.f, 0.f, 0.f, 0.f};
#pragma unroll
        for (int n = 0; n < 4; ++n) {
            int jl = wn * 64 + n * 16 + lr;         // 0..127
#pragma unroll
            for (int r = 0; r < 4; ++r) {
                int rl = wm * 64 + m * 16 + lg * 4 + r;   // 0..127
                float sim = acc[m][n][r] * INV_T;
                float e = __expf(sim - INV_T);
                rexp[r] += e;
                cexp[n] += e;
                float w1v = fp82f(wl1[rl * 128 + (((jl >> 4) ^ (rl & 7)) << 4) + (jl & 15)]);
                float w2v = fp82f(wl2[jl * 128 + (((rl >> 4) ^ (jl & 7)) << 4) + (rl & 15)]);
                d1 += (w1v + w2v) * sim;
            }
        }
#pragma unroll
        for (int r = 0; r < 4; ++r) {
            float v = rexp[r];
            v += __shfl_xor(v, 1); v += __shfl_xor(v, 2);
            v += __shfl_xor(v, 4); v += __shfl_xor(v, 8);
            if (lr == 0)
                atomicAdd(&rowTgt[rowBase + wm * 64 + m * 16 + lg * 4 + r], v);
        }
    }

    // col-exp sums: cross always; symmetric only for offdiag tiles
    if (mode == 0 || offdiag) {
#pragma unroll
        for (int n = 0; n < 4; ++n) {
            float v = cexp[n];
            v += __shfl_xor(v, 16); v += __shfl_xor(v, 32);
            if (lg == 0)
                atomicAdd(&colTgt[colBase + wn * 64 + n * 16 + lr], v);
        }
    }

    // weighted dot: (W + W^T) covers (i,j)+(j,i). diag sym tile counts half.
    float dtot = (mode != 0 && !offdiag) ? 0.5f * d1 : d1;
    for (int off = 32; off; off >>= 1) dtot += __shfl_xor(dtot, off);
    if (lane == 0) {
        float* dots = outs + 16384;
        if (mode == 0) atomicAdd(&dots[0], dtot);
        else           atomicAdd(&dots[1 + mode], dtot);
    }
}

// ---------------- kernel 4: finalize --------------------------------------
__global__ __launch_bounds__(256) void finalize_kernel(
        const float* __restrict__ outs, const float* __restrict__ flag,
        float* __restrict__ out) {
    const float* rowsum1 = outs;
    const float* colsum1 = outs + 4096;
    const float* rowsum3 = outs + 8192;
    const float* rowsum4 = outs + 12288;
    const float* dots = outs + 16384;
    int tid = threadIdx.x;
    float l = 0.f;
    for (int i = tid; i < NB; i += 256) {
        if (flag[i] != 0.f) {
            l += 4.f * INV_T + logf(rowsum1[i]) + logf(colsum1[i]) +
                 logf(rowsum3[i]) + logf(rowsum4[i]);
        }
    }
    for (int off = 32; off; off >>= 1) l += __shfl_down(l, off);
    __shared__ float red[4];
    int lane = tid & 63, w = tid >> 6;
    if (lane == 0) red[w] = l;
    __syncthreads();
    if (tid == 0) {
        float L = red[0] + red[1] + red[2] + red[3];
        float dt = dots[0] + dots[1] + dots[2] + dots[3];
        out[0] = (L - dt) / (4.0f * (float)NB);
    }
}

extern "C" void kernel_launch(void* const* d_in, const int* in_sizes, int n_in,
                              void* d_out, int out_size, void* d_ws, size_t ws_size,
                              hipStream_t stream) {
    const float* M = (const float*)d_in[0];
    const float* P = (const float*)d_in[1];
    const int* labels = (const int*)d_in[2];
    const int* sm = (const int*)d_in[3];
    const int* sp = (const int*)d_in[4];
    const float* cs = (const float*)d_in[5];
    float* out = (float*)d_out;

    char* ws = (char*)d_ws;
    unsigned char* Mf = (unsigned char*)ws;                                // 4 MB
    unsigned char* Pf = (unsigned char*)(ws + (size_t)4 * 1024 * 1024);    // 4 MB
    unsigned char* W = (unsigned char*)(ws + (size_t)16 * 1024 * 1024);    // 16 MB
    char* p = ws + (size_t)48 * 1024 * 1024;
    int* code = (int*)p;    p += 16384;
    float* flag = (float*)p; p += 16384;
    float* outs = (float*)p;   // rowsum1|colsum1|rowsum3|rowsum4|dots

    // zero rowsum1..rowsum4 (4 x 16KB) + dots (256 B)
    hipMemsetAsync(outs, 0, 4 * 16384 + 256, stream);

    norm_kernel<<<2 * NB, 256, 0, stream>>>(M, P, Mf, Pf);
    key_kernel<<<NB / 256, 256, 0, stream>>>(labels, sm, sp, code);
    rowsumw_kernel<<<NB, 256, 0, stream>>>(cs, code, W, flag);

    mega_gemm<<<2080, 256, 0, stream>>>(Mf, Pf, W, outs);

    finalize_kernel<<<1, 256, 0, stream>>>(outs, flag, out);
}

// Round 19
// 188.307 us; speedup vs baseline: 1.1323x; 1.0311x over previous
//
#include <hip/hip_runtime.h>
#include <hip/hip_bf16.h>
#include <hip/hip_fp8.h>
#include <math.h>

typedef __attribute__((ext_vector_type(4))) float f32x4;

#define NB 4096
#define ND 1024
#define INV_T 14.2857142857142857f   // 1/0.07

__device__ inline float fp82f(unsigned char b) {
    __hip_fp8_e4m3 h; h.__x = b;
    return (float)h;
}
__device__ inline void gload16(const void* g, void* l) {
    __builtin_amdgcn_global_load_lds(
        (const __attribute__((address_space(1))) void*)g,
        (__attribute__((address_space(3))) void*)l, 16, 0, 0);
}

// ---------------- kernel 0: L2-normalize rows, cast to fp8 e4m3 -------------
__global__ __launch_bounds__(256) void norm_kernel(
        const float* __restrict__ M, const float* __restrict__ P,
        unsigned char* __restrict__ Mf, unsigned char* __restrict__ Pf) {
    int row = blockIdx.x & (NB - 1);
    const float* src = (blockIdx.x < NB) ? M : P;
    unsigned char* dst = (blockIdx.x < NB) ? Mf : Pf;
    int tid = threadIdx.x;
    float4 v = ((const float4*)(src + (size_t)row * ND))[tid];
    float ss = v.x * v.x + v.y * v.y + v.z * v.z + v.w * v.w;
    for (int off = 32; off; off >>= 1) ss += __shfl_down(ss, off);
    __shared__ float red[4];
    int lane = tid & 63, w = tid >> 6;
    if (lane == 0) red[w] = ss;
    __syncthreads();
    float rn = rsqrtf(red[0] + red[1] + red[2] + red[3]);
    int p = __builtin_amdgcn_cvt_pk_fp8_f32(v.x * rn, v.y * rn, 0, false);
    p = __builtin_amdgcn_cvt_pk_fp8_f32(v.z * rn, v.w * rn, p, true);
    ((int*)dst)[row * 256 + tid] = p;
}

// ---------------- kernel 1: per-row mask codes ------------------------------
__global__ __launch_bounds__(256) void key_kernel(
        const int* __restrict__ labels, const int* __restrict__ sm,
        const int* __restrict__ sp, int* __restrict__ code) {
    int i = blockIdx.x * 256 + threadIdx.x;
    if (i < NB) {
        int l = labels[i];
        code[i] = (l == 0) ? 0x40000000 : (1 + l + (sm[i] << 8) + (sp[i] << 16));
    }
}

// ------- kernel 2: fused row-sum + normalized masked weight matrix (fp8) ----
__global__ __launch_bounds__(256) void rowsumw_kernel(
        const float* __restrict__ cs, const int* __restrict__ code,
        unsigned char* __restrict__ W, float* __restrict__ flag) {
    int i = blockIdx.x;
    int ci = code[i];
    int tid = threadIdx.x;
    const float4* row = (const float4*)(cs + (size_t)i * NB);
    const int4* c4 = (const int4*)code;
    float4 v[4];
    int4 cj[4];
    float s = 0.f;
#pragma unroll
    for (int k = 0; k < 4; ++k) {
        int t = tid + k * 256;
        v[k] = row[t];
        cj[k] = c4[t];
        int j = t * 4;
        if (cj[k].x == ci && j + 0 != i) s += v[k].x;
        if (cj[k].y == ci && j + 1 != i) s += v[k].y;
        if (cj[k].z == ci && j + 2 != i) s += v[k].z;
        if (cj[k].w == ci && j + 3 != i) s += v[k].w;
    }
    for (int off = 1; off < 64; off <<= 1) s += __shfl_xor(s, off);
    __shared__ float red[4];
    int lane = tid & 63, w = tid >> 6;
    if (lane == 0) red[w] = s;
    __syncthreads();
    float tot = red[0] + red[1] + red[2] + red[3];
    float inv = (tot > 0.f) ? 1.f / tot : 0.f;
#pragma unroll
    for (int k = 0; k < 4; ++k) {
        int t = tid + k * 256;
        int j = t * 4;
        float f0 = (cj[k].x == ci && j + 0 != i) ? v[k].x * inv : 0.f;
        float f1 = (cj[k].y == ci && j + 1 != i) ? v[k].y * inv : 0.f;
        float f2 = (cj[k].z == ci && j + 2 != i) ? v[k].z * inv : 0.f;
        float f3 = (cj[k].w == ci && j + 3 != i) ? v[k].w * inv : 0.f;
        int p = __builtin_amdgcn_cvt_pk_fp8_f32(f0, f1, 0, false);
        p = __builtin_amdgcn_cvt_pk_fp8_f32(f2, f3, p, true);
        ((int*)W)[((size_t)i * NB + j) >> 2] = p;
    }
    if (tid == 0) flag[i] = (tot > 0.f) ? 1.f : 0.f;
}

// ---------------- kernel 3: 1-WAVE barrier-free fp8 64x64-tile GEMM ---------
// 8256 logical blocks (XCD-chunked, 8256 = 8*1032), 64 threads = ONE wave:
//   b < 4096: cross S1 = Mf Pf^T, 4x4-supertiled 64x64 grid.
//   b >= 4096: symmetric (Mf then Pf), upper-tri 2080 each.
// acc[4][4] (64 AGPR), ~90 arch VGPR, NO pin -> no spill; LDS 16KB/block ->
// ~10 independent self-paced waves/CU. ZERO s_barrier in the K-loop: each
// wave pipelines on counted vmcnt alone (AITER-style), eliminating the
// lockstep barrier-drain that capped R10-R18's staging at ~4 TB/s.
// K loop: 16 tiles BK=64 fp8, 2 x 8KB buffers, depth-1 vmcnt(8).
// Tail: W[i][j] / W[j][i] fp8 tiles prefetch into the freed buffer.
__global__ __launch_bounds__(64) void mega_gemm(
        const unsigned char* __restrict__ Mf, const unsigned char* __restrict__ Pf,
        const unsigned char* __restrict__ Wg,
        float* __restrict__ outs) {
    __shared__ char smem[16384] __attribute__((aligned(16)));

    int lane = threadIdx.x;
    int lr = lane & 15, lg = lane >> 4;

    // ---- block decode ----
    int b = (blockIdx.x & 7) * 1032 + (blockIdx.x >> 3);
    int bi, bj, mode;
    const unsigned char *A, *Bm;
    if (b < 4096) {
        int st = b >> 4;                    // supertile 0..255 (16x16 grid)
        int sb = b & 15;                    // 4x4 within supertile
        bi = (st >> 4) * 4 + (sb >> 2);
        bj = (st & 15) * 4 + (sb & 3);
        A = Mf; Bm = Pf; mode = 0;
    } else {
        int s = b - 4096;
        int md = (s >= 2080) ? 1 : 0;
        s -= md * 2080;
        bi = 0;
        while (s >= 64 - bi) { s -= 64 - bi; ++bi; }
        bj = bi + s;
        A = md ? Pf : Mf; Bm = A;
        mode = 1 + md;
    }
    bool offdiag = (bi != bj);
    size_t rowBase = (size_t)bi * 64;
    size_t colBase = (size_t)bj * 64;
    bool needW2 = (rowBase != colBase);
    float* rowTgt = outs + ((mode == 0) ? 0 : (mode == 1) ? 8192 : 12288);
    float* colTgt = (mode == 0) ? (outs + 4096) : rowTgt;

    // ---- staging addresses: 64B fp8 rows, 4 lanes/row, pre-swizzled chunk --
    int sr = lane >> 2;                        // row 0..15 within 1KB unit
    int scs = (lane & 3) ^ (sr & 3) ^ ((sr >> 2) & 3);   // 16B chunk
    const unsigned char* gA = A + (rowBase + sr) * ND + scs * 16;
    const unsigned char* gB = Bm + (colBase + sr) * ND + scs * 16;

    f32x4 acc[4][4] = {};

    // per tile: A 64x64B (4KB) + B 64x64B (4KB); 8 x 1KB issues per wave
#define STAGE(bufi, t) {                                                    \
        int k0_ = (t) * 64;                                                 \
        char* base_ = smem + (bufi) * 8192;                                 \
        _Pragma("unroll")                                                   \
        for (int c = 0; c < 4; ++c) {                                       \
            gload16(gA + (size_t)(c * 16) * ND + k0_, base_ + c * 1024);    \
            gload16(gB + (size_t)(c * 16) * ND + k0_, base_ + 4096 + c * 1024); \
        }                                                                   \
    }
// W-tile staging: 4KB = 64 rows x 64B, 4 x 1KB issues, same swizzle as A
#define STAGEW(dst, rbase, cbase) {                                         \
        _Pragma("unroll")                                                   \
        for (int c = 0; c < 4; ++c) {                                       \
            gload16(Wg + ((rbase) + c * 16 + sr) * (size_t)NB + (cbase) + scs * 16, \
                    (dst) + c * 1024);                                      \
        }                                                                   \
    }
#define COMPUTE(bufi) {                                                     \
        const unsigned char* sA = (const unsigned char*)(smem + (bufi) * 8192); \
        const unsigned char* sB = sA + 4096;                                \
        int rx = (lr & 3) ^ ((lr >> 2) & 3);                                \
        _Pragma("unroll")                                                   \
        for (int ks = 0; ks < 2; ++ks) {                                    \
            int cp = (((ks * 2) + (lg >> 1)) ^ rx) * 16 + (lg & 1) * 8;     \
            long av[4], bv[4];                                              \
            _Pragma("unroll")                                               \
            for (int n = 0; n < 4; ++n)                                     \
                bv[n] = *(const long*)&sB[(n * 16 + lr) * 64 + cp];         \
            _Pragma("unroll")                                               \
            for (int i = 0; i < 4; ++i)                                     \
                av[i] = *(const long*)&sA[(i * 16 + lr) * 64 + cp];         \
            _Pragma("unroll")                                               \
            for (int i = 0; i < 4; ++i)                                     \
                _Pragma("unroll")                                           \
                for (int n = 0; n < 4; ++n)                                 \
                    acc[i][n] = __builtin_amdgcn_mfma_f32_16x16x32_fp8_fp8( \
                        av[i], bv[n], acc[i][n], 0, 0, 0);                  \
        }                                                                   \
        asm volatile("s_waitcnt lgkmcnt(0)" ::: "memory");                  \
    }

    // barrier-free depth-1 pipeline: buffer t&1 holds tile t. 8 loads/tile.
    STAGE(0, 0);
    for (int t = 0; t < 15; ++t) {
        STAGE((t + 1) & 1, t + 1);
        asm volatile("s_waitcnt vmcnt(8)" ::: "memory");   // tile t ready
        COMPUTE(t & 1);
    }
    // staged through 15, computed through 14; buf0 (tile 14) is free.
    STAGEW(smem, rowBase, colBase);                        // W1 -> [0,4K)
    if (needW2) {
        STAGEW(smem + 4096, colBase, rowBase);             // W2 -> [4K,8K)
        asm volatile("s_waitcnt vmcnt(8)" ::: "memory");   // tile 15 ready
    } else {
        asm volatile("s_waitcnt vmcnt(4)" ::: "memory");   // tile 15 ready
    }
    COMPUTE(1);                                            // tile 15
    asm volatile("s_waitcnt vmcnt(0)" ::: "memory");       // W tiles ready
#undef STAGE
#undef STAGEW
#undef COMPUTE

    // ---- epilogue: W1 = W[i-tile][j-tile], W2 = W[j-tile][i-tile] ----
    const unsigned char* wl1 = (const unsigned char*)smem;
    const unsigned char* wl2 = needW2 ? (const unsigned char*)smem + 4096
                                      : (const unsigned char*)smem;
    float d1 = 0.f;
    float cexp[4] = {0.f, 0.f, 0.f, 0.f};

#pragma unroll
    for (int m = 0; m < 4; ++m) {
        float rexp[4] = {0.f, 0.f, 0.f, 0.f};
#pragma unroll
        for (int n = 0; n < 4; ++n) {
            int jl = n * 16 + lr;               // 0..63
#pragma unroll
            for (int r = 0; r < 4; ++r) {
                int rl = m * 16 + lg * 4 + r;   // 0..63
                float sim = acc[m][n][r] * INV_T;
                float e = __expf(sim - INV_T);
                rexp[r] += e;
                cexp[n] += e;
                float w1v = fp82f(wl1[rl * 64 +
                    (((jl >> 4) ^ (rl & 3) ^ ((rl >> 2) & 3)) << 4) + (jl & 15)]);
                float w2v = fp82f(wl2[jl * 64 +
                    (((rl >> 4) ^ (jl & 3) ^ ((jl >> 2) & 3)) << 4) + (rl & 15)]);
                d1 += (w1v + w2v) * sim;
            }
        }
#pragma unroll
        for (int r = 0; r < 4; ++r) {
            float v = rexp[r];
            v += __shfl_xor(v, 1); v += __shfl_xor(v, 2);
            v += __shfl_xor(v, 4); v += __shfl_xor(v, 8);
            if (lr == 0)
                atomicAdd(&rowTgt[rowBase + m * 16 + lg * 4 + r], v);
        }
    }

    // col-exp sums: cross always; symmetric only for offdiag tiles
    if (mode == 0 || offdiag) {
#pragma unroll
        for (int n = 0; n < 4; ++n) {
            float v = cexp[n];
            v += __shfl_xor(v, 16); v += __shfl_xor(v, 32);
            if (lg == 0)
                atomicAdd(&colTgt[colBase + n * 16 + lr], v);
        }
    }

    // weighted dot: (W + W^T) covers (i,j)+(j,i). diag sym tile counts half.
    float dtot = (mode != 0 && !offdiag) ? 0.5f * d1 : d1;
    for (int off = 32; off; off >>= 1) dtot += __shfl_xor(dtot, off);
    if (lane == 0) {
        float* dots = outs + 16384;
        if (mode == 0) atomicAdd(&dots[0], dtot);
        else           atomicAdd(&dots[1 + mode], dtot);
    }
}

// ---------------- kernel 4: finalize --------------------------------------
__global__ __launch_bounds__(256) void finalize_kernel(
        const float* __restrict__ outs, const float* __restrict__ flag,
        float* __restrict__ out) {
    const float* rowsum1 = outs;
    const float* colsum1 = outs + 4096;
    const float* rowsum3 = outs + 8192;
    const float* rowsum4 = outs + 12288;
    const float* dots = outs + 16384;
    int tid = threadIdx.x;
    float l = 0.f;
    for (int i = tid; i < NB; i += 256) {
        if (flag[i] != 0.f) {
            l += 4.f * INV_T + logf(rowsum1[i]) + logf(colsum1[i]) +
                 logf(rowsum3[i]) + logf(rowsum4[i]);
        }
    }
    for (int off = 32; off; off >>= 1) l += __shfl_down(l, off);
    __shared__ float red[4];
    int lane = tid & 63, w = tid >> 6;
    if (lane == 0) red[w] = l;
    __syncthreads();
    if (tid == 0) {
        float L = red[0] + red[1] + red[2] + red[3];
        float dt = dots[0] + dots[1] + dots[2] + dots[3];
        out[0] = (L - dt) / (4.0f * (float)NB);
    }
}

extern "C" void kernel_launch(void* const* d_in, const int* in_sizes, int n_in,
                              void* d_out, int out_size, void* d_ws, size_t ws_size,
                              hipStream_t stream) {
    const float* M = (const float*)d_in[0];
    const float* P = (const float*)d_in[1];
    const int* labels = (const int*)d_in[2];
    const int* sm = (const int*)d_in[3];
    const int* sp = (const int*)d_in[4];
    const float* cs = (const float*)d_in[5];
    float* out = (float*)d_out;

    char* ws = (char*)d_ws;
    unsigned char* Mf = (unsigned char*)ws;                                // 4 MB
    unsigned char* Pf = (unsigned char*)(ws + (size_t)4 * 1024 * 1024);    // 4 MB
    unsigned char* W = (unsigned char*)(ws + (size_t)16 * 1024 * 1024);    // 16 MB
    char* p = ws + (size_t)48 * 1024 * 1024;
    int* code = (int*)p;    p += 16384;
    float* flag = (float*)p; p += 16384;
    float* outs = (float*)p;   // rowsum1|colsum1|rowsum3|rowsum4|dots

    hipMemsetAsync(outs, 0, 4 * 16384 + 256, stream);

    norm_kernel<<<2 * NB, 256, 0, stream>>>(M, P, Mf, Pf);
    key_kernel<<<NB / 256, 256, 0, stream>>>(labels, sm, sp, code);
    rowsumw_kernel<<<NB, 256, 0, stream>>>(cs, code, W, flag);

    mega_gemm<<<8256, 64, 0, stream>>>(Mf, Pf, W, outs);

    finalize_kernel<<<1, 256, 0, stream>>>(outs, flag, out);
}

// Round 20
// 185.619 us; speedup vs baseline: 1.1487x; 1.0145x over previous
//
#include <hip/hip_runtime.h>
#include <hip/hip_bf16.h>
#include <hip/hip_fp8.h>
#include <math.h>

typedef __attribute__((ext_vector_type(4))) float f32x4;

#define NB 4096
#define ND 1024
#define INV_T 14.2857142857142857f   // 1/0.07

__device__ inline float fp82f(unsigned char b) {
    __hip_fp8_e4m3 h; h.__x = b;
    return (float)h;
}
__device__ inline void gload16(const void* g, void* l) {
    __builtin_amdgcn_global_load_lds(
        (const __attribute__((address_space(1))) void*)g,
        (__attribute__((address_space(3))) void*)l, 16, 0, 0);
}

// ---------------- kernel 0: L2-normalize rows, cast to fp8 e4m3 -------------
__global__ __launch_bounds__(256) void norm_kernel(
        const float* __restrict__ M, const float* __restrict__ P,
        unsigned char* __restrict__ Mf, unsigned char* __restrict__ Pf) {
    int row = blockIdx.x & (NB - 1);
    const float* src = (blockIdx.x < NB) ? M : P;
    unsigned char* dst = (blockIdx.x < NB) ? Mf : Pf;
    int tid = threadIdx.x;
    float4 v = ((const float4*)(src + (size_t)row * ND))[tid];
    float ss = v.x * v.x + v.y * v.y + v.z * v.z + v.w * v.w;
    for (int off = 32; off; off >>= 1) ss += __shfl_down(ss, off);
    __shared__ float red[4];
    int lane = tid & 63, w = tid >> 6;
    if (lane == 0) red[w] = ss;
    __syncthreads();
    float rn = rsqrtf(red[0] + red[1] + red[2] + red[3]);
    int p = __builtin_amdgcn_cvt_pk_fp8_f32(v.x * rn, v.y * rn, 0, false);
    p = __builtin_amdgcn_cvt_pk_fp8_f32(v.z * rn, v.w * rn, p, true);
    ((int*)dst)[row * 256 + tid] = p;
}

// ---------------- kernel 1: per-row mask codes ------------------------------
__global__ __launch_bounds__(256) void key_kernel(
        const int* __restrict__ labels, const int* __restrict__ sm,
        const int* __restrict__ sp, int* __restrict__ code) {
    int i = blockIdx.x * 256 + threadIdx.x;
    if (i < NB) {
        int l = labels[i];
        code[i] = (l == 0) ? 0x40000000 : (1 + l + (sm[i] << 8) + (sp[i] << 16));
    }
}

// ------- kernel 2: fused row-sum + normalized masked weight matrix (fp8) ----
__global__ __launch_bounds__(256) void rowsumw_kernel(
        const float* __restrict__ cs, const int* __restrict__ code,
        unsigned char* __restrict__ W, float* __restrict__ flag) {
    int i = blockIdx.x;
    int ci = code[i];
    int tid = threadIdx.x;
    const float4* row = (const float4*)(cs + (size_t)i * NB);
    const int4* c4 = (const int4*)code;
    float4 v[4];
    int4 cj[4];
    float s = 0.f;
#pragma unroll
    for (int k = 0; k < 4; ++k) {
        int t = tid + k * 256;
        v[k] = row[t];
        cj[k] = c4[t];
        int j = t * 4;
        if (cj[k].x == ci && j + 0 != i) s += v[k].x;
        if (cj[k].y == ci && j + 1 != i) s += v[k].y;
        if (cj[k].z == ci && j + 2 != i) s += v[k].z;
        if (cj[k].w == ci && j + 3 != i) s += v[k].w;
    }
    for (int off = 1; off < 64; off <<= 1) s += __shfl_xor(s, off);
    __shared__ float red[4];
    int lane = tid & 63, w = tid >> 6;
    if (lane == 0) red[w] = s;
    __syncthreads();
    float tot = red[0] + red[1] + red[2] + red[3];
    float inv = (tot > 0.f) ? 1.f / tot : 0.f;
#pragma unroll
    for (int k = 0; k < 4; ++k) {
        int t = tid + k * 256;
        int j = t * 4;
        float f0 = (cj[k].x == ci && j + 0 != i) ? v[k].x * inv : 0.f;
        float f1 = (cj[k].y == ci && j + 1 != i) ? v[k].y * inv : 0.f;
        float f2 = (cj[k].z == ci && j + 2 != i) ? v[k].z * inv : 0.f;
        float f3 = (cj[k].w == ci && j + 3 != i) ? v[k].w * inv : 0.f;
        int p = __builtin_amdgcn_cvt_pk_fp8_f32(f0, f1, 0, false);
        p = __builtin_amdgcn_cvt_pk_fp8_f32(f2, f3, p, true);
        ((int*)W)[((size_t)i * NB + j) >> 2] = p;
    }
    if (tid == 0) flag[i] = (tot > 0.f) ? 1.f : 0.f;
}

// ---------------- kernel 3: 1-WAVE barrier-free fp8 64x64-tile GEMM ---------
// 8256 logical blocks (XCD-chunked, 8256 = 8*1032), 64 threads = ONE wave:
//   b < 4096: cross S1 = Mf Pf^T, 4x4-supertiled 64x64 grid.
//   b >= 4096: symmetric (Mf then Pf), upper-tri 2080 each.
// acc[4][4] (64 AGPR), ~176 arch VGPR, no pin, no spill (R19-verified).
// R20 change: depth-2 pipeline over THREE 8KB buffers (24KB LDS) — vmcnt
// cover doubles from ~300cy (1 compute step) to ~600cy >= L2/L3 load-return
// latency, so the self-paced wave's per-step stall goes to ~0. Uniform tail:
// both W tiles always staged into the freed buffer (counts 16->8->0).
__global__ __launch_bounds__(64) void mega_gemm(
        const unsigned char* __restrict__ Mf, const unsigned char* __restrict__ Pf,
        const unsigned char* __restrict__ Wg,
        float* __restrict__ outs) {
    __shared__ char smem[24576] __attribute__((aligned(16)));

    int lane = threadIdx.x;
    int lr = lane & 15, lg = lane >> 4;

    // ---- block decode ----
    int b = (blockIdx.x & 7) * 1032 + (blockIdx.x >> 3);
    int bi, bj, mode;
    const unsigned char *A, *Bm;
    if (b < 4096) {
        int st = b >> 4;                    // supertile 0..255 (16x16 grid)
        int sb = b & 15;                    // 4x4 within supertile
        bi = (st >> 4) * 4 + (sb >> 2);
        bj = (st & 15) * 4 + (sb & 3);
        A = Mf; Bm = Pf; mode = 0;
    } else {
        int s = b - 4096;
        int md = (s >= 2080) ? 1 : 0;
        s -= md * 2080;
        bi = 0;
        while (s >= 64 - bi) { s -= 64 - bi; ++bi; }
        bj = bi + s;
        A = md ? Pf : Mf; Bm = A;
        mode = 1 + md;
    }
    bool offdiag = (bi != bj);
    size_t rowBase = (size_t)bi * 64;
    size_t colBase = (size_t)bj * 64;
    float* rowTgt = outs + ((mode == 0) ? 0 : (mode == 1) ? 8192 : 12288);
    float* colTgt = (mode == 0) ? (outs + 4096) : rowTgt;

    // ---- staging addresses: 64B fp8 rows, 4 lanes/row, pre-swizzled chunk --
    int sr = lane >> 2;                        // row 0..15 within 1KB unit
    int scs = (lane & 3) ^ (sr & 3) ^ ((sr >> 2) & 3);   // 16B chunk
    const unsigned char* gA = A + (rowBase + sr) * ND + scs * 16;
    const unsigned char* gB = Bm + (colBase + sr) * ND + scs * 16;

    f32x4 acc[4][4] = {};

    // per tile: A 64x64B (4KB) + B 64x64B (4KB); 8 x 1KB issues per wave
#define STAGE(bufi, t) {                                                    \
        int k0_ = (t) * 64;                                                 \
        char* base_ = smem + (bufi) * 8192;                                 \
        _Pragma("unroll")                                                   \
        for (int c = 0; c < 4; ++c) {                                       \
            gload16(gA + (size_t)(c * 16) * ND + k0_, base_ + c * 1024);    \
            gload16(gB + (size_t)(c * 16) * ND + k0_, base_ + 4096 + c * 1024); \
        }                                                                   \
    }
// W-tile staging: 4KB = 64 rows x 64B, 4 x 1KB issues, same swizzle as A
#define STAGEW(dst, rbase, cbase) {                                         \
        _Pragma("unroll")                                                   \
        for (int c = 0; c < 4; ++c) {                                       \
            gload16(Wg + ((rbase) + c * 16 + sr) * (size_t)NB + (cbase) + scs * 16, \
                    (dst) + c * 1024);                                      \
        }                                                                   \
    }
#define COMPUTE(bufi) {                                                     \
        const unsigned char* sA = (const unsigned char*)(smem + (bufi) * 8192); \
        const unsigned char* sB = sA + 4096;                                \
        int rx = (lr & 3) ^ ((lr >> 2) & 3);                                \
        _Pragma("unroll")                                                   \
        for (int ks = 0; ks < 2; ++ks) {                                    \
            int cp = (((ks * 2) + (lg >> 1)) ^ rx) * 16 + (lg & 1) * 8;     \
            long av[4], bv[4];                                              \
            _Pragma("unroll")                                               \
            for (int n = 0; n < 4; ++n)                                     \
                bv[n] = *(const long*)&sB[(n * 16 + lr) * 64 + cp];         \
            _Pragma("unroll")                                               \
            for (int i = 0; i < 4; ++i)                                     \
                av[i] = *(const long*)&sA[(i * 16 + lr) * 64 + cp];         \
            _Pragma("unroll")                                               \
            for (int i = 0; i < 4; ++i)                                     \
                _Pragma("unroll")                                           \
                for (int n = 0; n < 4; ++n)                                 \
                    acc[i][n] = __builtin_amdgcn_mfma_f32_16x16x32_fp8_fp8( \
                        av[i], bv[n], acc[i][n], 0, 0, 0);                  \
        }                                                                   \
        asm volatile("s_waitcnt lgkmcnt(0)" ::: "memory");                  \
    }

    // barrier-free depth-2 pipeline: tile t lives in buffer t%3.
    STAGE(0, 0); STAGE(1, 1);                              // 16 outstanding
    for (int t = 0; t < 14; ++t) {
        STAGE((t + 2) % 3, t + 2);                         // 24 outstanding
        asm volatile("s_waitcnt vmcnt(16)" ::: "memory");  // tile t ready
        COMPUTE(t % 3);
    }
    // computed through 13; outstanding: tile 14 (buf2), tile 15 (buf0) = 16.
    // buf1 (tile 13) is free -> stage both W tiles there (8 loads -> 24).
    STAGEW(smem + 8192, rowBase, colBase);                 // W1
    STAGEW(smem + 12288, colBase, rowBase);                // W2 (diag: dup)
    asm volatile("s_waitcnt vmcnt(16)" ::: "memory");      // tile 14 ready
    COMPUTE(2);
    asm volatile("s_waitcnt vmcnt(8)" ::: "memory");       // tile 15 ready
    COMPUTE(0);
    asm volatile("s_waitcnt vmcnt(0)" ::: "memory");       // W tiles ready
#undef STAGE
#undef STAGEW
#undef COMPUTE

    // ---- epilogue: W1 = W[i-tile][j-tile], W2 = W[j-tile][i-tile] ----
    const unsigned char* wl1 = (const unsigned char*)smem + 8192;
    const unsigned char* wl2 = (const unsigned char*)smem + 12288;
    float d1 = 0.f;
    float cexp[4] = {0.f, 0.f, 0.f, 0.f};

#pragma unroll
    for (int m = 0; m < 4; ++m) {
        float rexp[4] = {0.f, 0.f, 0.f, 0.f};
#pragma unroll
        for (int n = 0; n < 4; ++n) {
            int jl = n * 16 + lr;               // 0..63
#pragma unroll
            for (int r = 0; r < 4; ++r) {
                int rl = m * 16 + lg * 4 + r;   // 0..63
                float sim = acc[m][n][r] * INV_T;
                float e = __expf(sim - INV_T);
                rexp[r] += e;
                cexp[n] += e;
                float w1v = fp82f(wl1[rl * 64 +
                    (((jl >> 4) ^ (rl & 3) ^ ((rl >> 2) & 3)) << 4) + (jl & 15)]);
                float w2v = fp82f(wl2[jl * 64 +
                    (((rl >> 4) ^ (jl & 3) ^ ((jl >> 2) & 3)) << 4) + (rl & 15)]);
                d1 += (w1v + w2v) * sim;
            }
        }
#pragma unroll
        for (int r = 0; r < 4; ++r) {
            float v = rexp[r];
            v += __shfl_xor(v, 1); v += __shfl_xor(v, 2);
            v += __shfl_xor(v, 4); v += __shfl_xor(v, 8);
            if (lr == 0)
                atomicAdd(&rowTgt[rowBase + m * 16 + lg * 4 + r], v);
        }
    }

    // col-exp sums: cross always; symmetric only for offdiag tiles
    if (mode == 0 || offdiag) {
#pragma unroll
        for (int n = 0; n < 4; ++n) {
            float v = cexp[n];
            v += __shfl_xor(v, 16); v += __shfl_xor(v, 32);
            if (lg == 0)
                atomicAdd(&colTgt[colBase + n * 16 + lr], v);
        }
    }

    // weighted dot: (W + W^T) covers (i,j)+(j,i). diag sym tile counts half.
    float dtot = (mode != 0 && !offdiag) ? 0.5f * d1 : d1;
    for (int off = 32; off; off >>= 1) dtot += __shfl_xor(dtot, off);
    if (lane == 0) {
        float* dots = outs + 16384;
        if (mode == 0) atomicAdd(&dots[0], dtot);
        else           atomicAdd(&dots[1 + mode], dtot);
    }
}

// ---------------- kernel 4: finalize --------------------------------------
__global__ __launch_bounds__(256) void finalize_kernel(
        const float* __restrict__ outs, const float* __restrict__ flag,
        float* __restrict__ out) {
    const float* rowsum1 = outs;
    const float* colsum1 = outs + 4096;
    const float* rowsum3 = outs + 8192;
    const float* rowsum4 = outs + 12288;
    const float* dots = outs + 16384;
    int tid = threadIdx.x;
    float l = 0.f;
    for (int i = tid; i < NB; i += 256) {
        if (flag[i] != 0.f) {
            l += 4.f * INV_T + logf(rowsum1[i]) + logf(colsum1[i]) +
                 logf(rowsum3[i]) + logf(rowsum4[i]);
        }
    }
    for (int off = 32; off; off >>= 1) l += __shfl_down(l, off);
    __shared__ float red[4];
    int lane = tid & 63, w = tid >> 6;
    if (lane == 0) red[w] = l;
    __syncthreads();
    if (tid == 0) {
        float L = red[0] + red[1] + red[2] + red[3];
        float dt = dots[0] + dots[1] + dots[2] + dots[3];
        out[0] = (L - dt) / (4.0f * (float)NB);
    }
}

extern "C" void kernel_launch(void* const* d_in, const int* in_sizes, int n_in,
                              void* d_out, int out_size, void* d_ws, size_t ws_size,
                              hipStream_t stream) {
    const float* M = (const float*)d_in[0];
    const float* P = (const float*)d_in[1];
    const int* labels = (const int*)d_in[2];
    const int* sm = (const int*)d_in[3];
    const int* sp = (const int*)d_in[4];
    const float* cs = (const float*)d_in[5];
    float* out = (float*)d_out;

    char* ws = (char*)d_ws;
    unsigned char* Mf = (unsigned char*)ws;                                // 4 MB
    unsigned char* Pf = (unsigned char*)(ws + (size_t)4 * 1024 * 1024);    // 4 MB
    unsigned char* W = (unsigned char*)(ws + (size_t)16 * 1024 * 1024);    // 16 MB
    char* p = ws + (size_t)48 * 1024 * 1024;
    int* code = (int*)p;    p += 16384;
    float* flag = (float*)p; p += 16384;
    float* outs = (float*)p;   // rowsum1|colsum1|rowsum3|rowsum4|dots

    hipMemsetAsync(outs, 0, 4 * 16384 + 256, stream);

    norm_kernel<<<2 * NB, 256, 0, stream>>>(M, P, Mf, Pf);
    key_kernel<<<NB / 256, 256, 0, stream>>>(labels, sm, sp, code);
    rowsumw_kernel<<<NB, 256, 0, stream>>>(cs, code, W, flag);

    mega_gemm<<<8256, 64, 0, stream>>>(Mf, Pf, W, outs);

    finalize_kernel<<<1, 256, 0, stream>>>(outs, flag, out);
}

// Round 21
// 183.484 us; speedup vs baseline: 1.1620x; 1.0116x over previous
//
#include <hip/hip_runtime.h>
#include <hip/hip_bf16.h>
#include <hip/hip_fp8.h>
#include <math.h>

typedef __attribute__((ext_vector_type(4))) float f32x4;

#define NB 4096
#define ND 1024
#define INV_T 14.2857142857142857f   // 1/0.07

__device__ inline float fp82f(unsigned char b) {
    __hip_fp8_e4m3 h; h.__x = b;
    return (float)h;
}
__device__ inline void gload16(const void* g, void* l) {
    __builtin_amdgcn_global_load_lds(
        (const __attribute__((address_space(1))) void*)g,
        (__attribute__((address_space(3))) void*)l, 16, 0, 0);
}

// ---------------- kernel 0: L2-normalize rows, cast to fp8 e4m3 -------------
__global__ __launch_bounds__(256) void norm_kernel(
        const float* __restrict__ M, const float* __restrict__ P,
        unsigned char* __restrict__ Mf, unsigned char* __restrict__ Pf) {
    int row = blockIdx.x & (NB - 1);
    const float* src = (blockIdx.x < NB) ? M : P;
    unsigned char* dst = (blockIdx.x < NB) ? Mf : Pf;
    int tid = threadIdx.x;
    float4 v = ((const float4*)(src + (size_t)row * ND))[tid];
    float ss = v.x * v.x + v.y * v.y + v.z * v.z + v.w * v.w;
    for (int off = 32; off; off >>= 1) ss += __shfl_down(ss, off);
    __shared__ float red[4];
    int lane = tid & 63, w = tid >> 6;
    if (lane == 0) red[w] = ss;
    __syncthreads();
    float rn = rsqrtf(red[0] + red[1] + red[2] + red[3]);
    int p = __builtin_amdgcn_cvt_pk_fp8_f32(v.x * rn, v.y * rn, 0, false);
    p = __builtin_amdgcn_cvt_pk_fp8_f32(v.z * rn, v.w * rn, p, true);
    ((int*)dst)[row * 256 + tid] = p;
}

// ---------------- kernel 1: per-row mask codes ------------------------------
__global__ __launch_bounds__(256) void key_kernel(
        const int* __restrict__ labels, const int* __restrict__ sm,
        const int* __restrict__ sp, int* __restrict__ code) {
    int i = blockIdx.x * 256 + threadIdx.x;
    if (i < NB) {
        int l = labels[i];
        code[i] = (l == 0) ? 0x40000000 : (1 + l + (sm[i] << 8) + (sp[i] << 16));
    }
}

// ------- kernel 2: fused row-sum + normalized masked weight matrix (fp8) ----
__global__ __launch_bounds__(256) void rowsumw_kernel(
        const float* __restrict__ cs, const int* __restrict__ code,
        unsigned char* __restrict__ W, float* __restrict__ flag) {
    int i = blockIdx.x;
    int ci = code[i];
    int tid = threadIdx.x;
    const float4* row = (const float4*)(cs + (size_t)i * NB);
    const int4* c4 = (const int4*)code;
    float4 v[4];
    int4 cj[4];
    float s = 0.f;
#pragma unroll
    for (int k = 0; k < 4; ++k) {
        int t = tid + k * 256;
        v[k] = row[t];
        cj[k] = c4[t];
        int j = t * 4;
        if (cj[k].x == ci && j + 0 != i) s += v[k].x;
        if (cj[k].y == ci && j + 1 != i) s += v[k].y;
        if (cj[k].z == ci && j + 2 != i) s += v[k].z;
        if (cj[k].w == ci && j + 3 != i) s += v[k].w;
    }
    for (int off = 1; off < 64; off <<= 1) s += __shfl_xor(s, off);
    __shared__ float red[4];
    int lane = tid & 63, w = tid >> 6;
    if (lane == 0) red[w] = s;
    __syncthreads();
    float tot = red[0] + red[1] + red[2] + red[3];
    float inv = (tot > 0.f) ? 1.f / tot : 0.f;
#pragma unroll
    for (int k = 0; k < 4; ++k) {
        int t = tid + k * 256;
        int j = t * 4;
        float f0 = (cj[k].x == ci && j + 0 != i) ? v[k].x * inv : 0.f;
        float f1 = (cj[k].y == ci && j + 1 != i) ? v[k].y * inv : 0.f;
        float f2 = (cj[k].z == ci && j + 2 != i) ? v[k].z * inv : 0.f;
        float f3 = (cj[k].w == ci && j + 3 != i) ? v[k].w * inv : 0.f;
        int p = __builtin_amdgcn_cvt_pk_fp8_f32(f0, f1, 0, false);
        p = __builtin_amdgcn_cvt_pk_fp8_f32(f2, f3, p, true);
        ((int*)W)[((size_t)i * NB + j) >> 2] = p;
    }
    if (tid == 0) flag[i] = (tot > 0.f) ? 1.f : 0.f;
}

// ---------------- kernel 3: 4x(1-wave) barrier-free fp8 64x64-tile GEMM -----
// 2064 workgroups (XCD-chunked, 2064 = 8*258) x 256 threads = 4 INDEPENDENT
// waves. Wave w owns logical tile b*4+w and a private 16KB LDS slice; zero
// __syncthreads anywhere. Same R19/R20-verified per-wave depth-1 pipeline.
// Rationale: R19/R20 occupancy stuck at ~3 waves/CU with 8256 one-wave
// workgroups -> CP dispatch rate bound (1 wg / ~370cy / XCD). 4 waves/wg
// quarters the dispatch count; LDS 64KB/wg -> 2 wg/CU -> 8 waves/CU.
//   tile < 4096: cross S1 = Mf Pf^T, 4x4-supertiled 64x64 grid.
//   tile >= 4096: symmetric (Mf then Pf), upper-tri 2080 each.
__global__ __launch_bounds__(256) void mega_gemm(
        const unsigned char* __restrict__ Mf, const unsigned char* __restrict__ Pf,
        const unsigned char* __restrict__ Wg,
        float* __restrict__ outs) {
    __shared__ char smem[65536] __attribute__((aligned(16)));

    int tid = threadIdx.x;
    int lane = tid & 63;
    char* bs = smem + (tid >> 6) * 16384;      // this wave's private slice
    int lr = lane & 15, lg = lane >> 4;

    // ---- tile decode ----
    int b = ((blockIdx.x & 7) * 258 + (blockIdx.x >> 3)) * 4 + (tid >> 6);
    int bi, bj, mode;
    const unsigned char *A, *Bm;
    if (b < 4096) {
        int st = b >> 4;                    // supertile 0..255 (16x16 grid)
        int sb = b & 15;                    // 4x4 within supertile
        bi = (st >> 4) * 4 + (sb >> 2);
        bj = (st & 15) * 4 + (sb & 3);
        A = Mf; Bm = Pf; mode = 0;
    } else {
        int s = b - 4096;
        int md = (s >= 2080) ? 1 : 0;
        s -= md * 2080;
        bi = 0;
        while (s >= 64 - bi) { s -= 64 - bi; ++bi; }
        bj = bi + s;
        A = md ? Pf : Mf; Bm = A;
        mode = 1 + md;
    }
    bool offdiag = (bi != bj);
    size_t rowBase = (size_t)bi * 64;
    size_t colBase = (size_t)bj * 64;
    bool needW2 = (rowBase != colBase);
    float* rowTgt = outs + ((mode == 0) ? 0 : (mode == 1) ? 8192 : 12288);
    float* colTgt = (mode == 0) ? (outs + 4096) : rowTgt;

    // ---- staging addresses: 64B fp8 rows, 4 lanes/row, pre-swizzled chunk --
    int sr = lane >> 2;                        // row 0..15 within 1KB unit
    int scs = (lane & 3) ^ (sr & 3) ^ ((sr >> 2) & 3);   // 16B chunk
    const unsigned char* gA = A + (rowBase + sr) * ND + scs * 16;
    const unsigned char* gB = Bm + (colBase + sr) * ND + scs * 16;

    f32x4 acc[4][4] = {};

    // per tile: A 64x64B (4KB) + B 64x64B (4KB); 8 x 1KB issues per wave
#define STAGE(bufi, t) {                                                    \
        int k0_ = (t) * 64;                                                 \
        char* base_ = bs + (bufi) * 8192;                                   \
        _Pragma("unroll")                                                   \
        for (int c = 0; c < 4; ++c) {                                       \
            gload16(gA + (size_t)(c * 16) * ND + k0_, base_ + c * 1024);    \
            gload16(gB + (size_t)(c * 16) * ND + k0_, base_ + 4096 + c * 1024); \
        }                                                                   \
    }
// W-tile staging: 4KB = 64 rows x 64B, 4 x 1KB issues, same swizzle as A
#define STAGEW(dst, rbase, cbase) {                                         \
        _Pragma("unroll")                                                   \
        for (int c = 0; c < 4; ++c) {                                       \
            gload16(Wg + ((rbase) + c * 16 + sr) * (size_t)NB + (cbase) + scs * 16, \
                    (dst) + c * 1024);                                      \
        }                                                                   \
    }
#define COMPUTE(bufi) {                                                     \
        const unsigned char* sA = (const unsigned char*)(bs + (bufi) * 8192); \
        const unsigned char* sB = sA + 4096;                                \
        int rx = (lr & 3) ^ ((lr >> 2) & 3);                                \
        _Pragma("unroll")                                                   \
        for (int ks = 0; ks < 2; ++ks) {                                    \
            int cp = (((ks * 2) + (lg >> 1)) ^ rx) * 16 + (lg & 1) * 8;     \
            long av[4], bv[4];                                              \
            _Pragma("unroll")                                               \
            for (int n = 0; n < 4; ++n)                                     \
                bv[n] = *(const long*)&sB[(n * 16 + lr) * 64 + cp];         \
            _Pragma("unroll")                                               \
            for (int i = 0; i < 4; ++i)                                     \
                av[i] = *(const long*)&sA[(i * 16 + lr) * 64 + cp];         \
            _Pragma("unroll")                                               \
            for (int i = 0; i < 4; ++i)                                     \
                _Pragma("unroll")                                           \
                for (int n = 0; n < 4; ++n)                                 \
                    acc[i][n] = __builtin_amdgcn_mfma_f32_16x16x32_fp8_fp8( \
                        av[i], bv[n], acc[i][n], 0, 0, 0);                  \
        }                                                                   \
        asm volatile("s_waitcnt lgkmcnt(0)" ::: "memory");                  \
    }

    // barrier-free depth-1 pipeline: buffer t&1 holds tile t. 8 loads/tile.
    STAGE(0, 0);
    for (int t = 0; t < 15; ++t) {
        STAGE((t + 1) & 1, t + 1);
        asm volatile("s_waitcnt vmcnt(8)" ::: "memory");   // tile t ready
        COMPUTE(t & 1);
    }
    // staged through 15, computed through 14; buf0 (tile 14) is free.
    STAGEW(bs, rowBase, colBase);                          // W1 -> [0,4K)
    if (needW2) {
        STAGEW(bs + 4096, colBase, rowBase);               // W2 -> [4K,8K)
        asm volatile("s_waitcnt vmcnt(8)" ::: "memory");   // tile 15 ready
    } else {
        asm volatile("s_waitcnt vmcnt(4)" ::: "memory");   // tile 15 ready
    }
    COMPUTE(1);                                            // tile 15
    asm volatile("s_waitcnt vmcnt(0)" ::: "memory");       // W tiles ready
#undef STAGE
#undef STAGEW
#undef COMPUTE

    // ---- epilogue: W1 = W[i-tile][j-tile], W2 = W[j-tile][i-tile] ----
    const unsigned char* wl1 = (const unsigned char*)bs;
    const unsigned char* wl2 = needW2 ? (const unsigned char*)bs + 4096
                                      : (const unsigned char*)bs;
    float d1 = 0.f;
    float cexp[4] = {0.f, 0.f, 0.f, 0.f};

#pragma unroll
    for (int m = 0; m < 4; ++m) {
        float rexp[4] = {0.f, 0.f, 0.f, 0.f};
#pragma unroll
        for (int n = 0; n < 4; ++n) {
            int jl = n * 16 + lr;               // 0..63
#pragma unroll
            for (int r = 0; r < 4; ++r) {
                int rl = m * 16 + lg * 4 + r;   // 0..63
                float sim = acc[m][n][r] * INV_T;
                float e = __expf(sim - INV_T);
                rexp[r] += e;
                cexp[n] += e;
                float w1v = fp82f(wl1[rl * 64 +
                    (((jl >> 4) ^ (rl & 3) ^ ((rl >> 2) & 3)) << 4) + (jl & 15)]);
                float w2v = fp82f(wl2[jl * 64 +
                    (((rl >> 4) ^ (jl & 3) ^ ((jl >> 2) & 3)) << 4) + (rl & 15)]);
                d1 += (w1v + w2v) * sim;
            }
        }
#pragma unroll
        for (int r = 0; r < 4; ++r) {
            float v = rexp[r];
            v += __shfl_xor(v, 1); v += __shfl_xor(v, 2);
            v += __shfl_xor(v, 4); v += __shfl_xor(v, 8);
            if (lr == 0)
                atomicAdd(&rowTgt[rowBase + m * 16 + lg * 4 + r], v);
        }
    }

    // col-exp sums: cross always; symmetric only for offdiag tiles
    if (mode == 0 || offdiag) {
#pragma unroll
        for (int n = 0; n < 4; ++n) {
            float v = cexp[n];
            v += __shfl_xor(v, 16); v += __shfl_xor(v, 32);
            if (lg == 0)
                atomicAdd(&colTgt[colBase + n * 16 + lr], v);
        }
    }

    // weighted dot: (W + W^T) covers (i,j)+(j,i). diag sym tile counts half.
    float dtot = (mode != 0 && !offdiag) ? 0.5f * d1 : d1;
    for (int off = 32; off; off >>= 1) dtot += __shfl_xor(dtot, off);
    if (lane == 0) {
        float* dots = outs + 16384;
        if (mode == 0) atomicAdd(&dots[0], dtot);
        else           atomicAdd(&dots[1 + mode], dtot);
    }
}

// ---------------- kernel 4: finalize --------------------------------------
__global__ __launch_bounds__(256) void finalize_kernel(
        const float* __restrict__ outs, const float* __restrict__ flag,
        float* __restrict__ out) {
    const float* rowsum1 = outs;
    const float* colsum1 = outs + 4096;
    const float* rowsum3 = outs + 8192;
    const float* rowsum4 = outs + 12288;
    const float* dots = outs + 16384;
    int tid = threadIdx.x;
    float l = 0.f;
    for (int i = tid; i < NB; i += 256) {
        if (flag[i] != 0.f) {
            l += 4.f * INV_T + logf(rowsum1[i]) + logf(colsum1[i]) +
                 logf(rowsum3[i]) + logf(rowsum4[i]);
        }
    }
    for (int off = 32; off; off >>= 1) l += __shfl_down(l, off);
    __shared__ float red[4];
    int lane = tid & 63, w = tid >> 6;
    if (lane == 0) red[w] = l;
    __syncthreads();
    if (tid == 0) {
        float L = red[0] + red[1] + red[2] + red[3];
        float dt = dots[0] + dots[1] + dots[2] + dots[3];
        out[0] = (L - dt) / (4.0f * (float)NB);
    }
}

extern "C" void kernel_launch(void* const* d_in, const int* in_sizes, int n_in,
                              void* d_out, int out_size, void* d_ws, size_t ws_size,
                              hipStream_t stream) {
    const float* M = (const float*)d_in[0];
    const float* P = (const float*)d_in[1];
    const int* labels = (const int*)d_in[2];
    const int* sm = (const int*)d_in[3];
    const int* sp = (const int*)d_in[4];
    const float* cs = (const float*)d_in[5];
    float* out = (float*)d_out;

    char* ws = (char*)d_ws;
    unsigned char* Mf = (unsigned char*)ws;                                // 4 MB
    unsigned char* Pf = (unsigned char*)(ws + (size_t)4 * 1024 * 1024);    // 4 MB
    unsigned char* W = (unsigned char*)(ws + (size_t)16 * 1024 * 1024);    // 16 MB
    char* p = ws + (size_t)48 * 1024 * 1024;
    int* code = (int*)p;    p += 16384;
    float* flag = (float*)p; p += 16384;
    float* outs = (float*)p;   // rowsum1|colsum1|rowsum3|rowsum4|dots

    hipMemsetAsync(outs, 0, 4 * 16384 + 256, stream);

    norm_kernel<<<2 * NB, 256, 0, stream>>>(M, P, Mf, Pf);
    key_kernel<<<NB / 256, 256, 0, stream>>>(labels, sm, sp, code);
    rowsumw_kernel<<<NB, 256, 0, stream>>>(cs, code, W, flag);

    mega_gemm<<<2064, 256, 0, stream>>>(Mf, Pf, W, outs);

    finalize_kernel<<<1, 256, 0, stream>>>(outs, flag, out);
}